// Round 6
// baseline (3080.980 us; speedup 1.0000x reference)
//
#include <hip/hip_runtime.h>
#include <hip/hip_bf16.h>
#include <math.h>

#define NB 128
#define NR 32
#define EPAD 40    // fA row stride in shorts
#define HPAD 136   // H/XA row stride in shorts (272B, 16B-aligned rows)

// r21: CHUNKED BISECTION. r20's split never ran: full-E Wbuf (410MB) blew
// ws_size -> fallback (profile showed edge_fused_mfma, dur=baseline).
// r21 carves Wbuf from the REMAINING workspace and loops edge chunks of
// chunkE=remaining/256B (multiple of 1024): filter(chunk) -> scatter(chunk).
// Chunks past the active count early-exit. Attribution unchanged:
//   A edge_filter_mfma: RBF->GEMM1->ssp->GEMM2, *rcut, coalesced bf16 Wij
//     store (permuted layout). No gather/atomics.
//   B edge_scatter: no LDS/MFMA/barriers; quad owns 16 contiguous edges
//     (cross-iter run merge), reads Wij coalesced, gathers xf, pk atomics.
// Falsified: r5 LDS gather staging, r6 owner-computes fusion, r7 permuted
// scatter, r10 pre-barrier gather, r12 analytic A-fragment, r14 2-tile
// pipeline, r16 LDS fp32 agg, r17 bigger tile, r18 cross-quad merge,
// r19 barrier-free (all neutral or worse), r20 unchunked split (never ran).

static constexpr float CUTOFF_F    = 10.0f;
static constexpr float RBF_STEP    = 10.0f / 31.0f;
static constexpr float RBF_COEFF   = -4.805f;           // -0.5/(10/31)^2
static constexpr float LOG2_F      = 0.69314718055994531f;
static constexpr float PI_OVER_CUT = 0.314159265358979f;

typedef __attribute__((ext_vector_type(8))) short bf16x8;
typedef __attribute__((ext_vector_type(2))) short bf16x2;
typedef __attribute__((ext_vector_type(4))) float f32x4;

__device__ __forceinline__ short f2bs(float x) {
    __hip_bfloat16 h = __float2bfloat16(x);   // RNE
    return *reinterpret_cast<short*>(&h);
}
__device__ __forceinline__ float bs2f(unsigned short u) {
    unsigned int v = ((unsigned int)u) << 16;
    return __uint_as_float(v);
}
__device__ __forceinline__ float ssp_f(float v) {
    return fmaxf(v, 0.0f) + __logf(1.0f + __expf(-fabsf(v))) - LOG2_F;
}
__device__ __forceinline__ float silu_f(float v) {
    return v / (1.0f + __expf(-v));
}

// packed bf16 atomic add (2 features per op)
__device__ __forceinline__ void atomic_pk_add_bf16(short* addr, float lo, float hi) {
#if __has_builtin(__builtin_amdgcn_global_atomic_fadd_v2bf16)
    typedef bf16x2 __attribute__((address_space(1))) *gptr;
    bf16x2 v;
    v[0] = f2bs(lo);
    v[1] = f2bs(hi);
    __builtin_amdgcn_global_atomic_fadd_v2bf16((gptr)(unsigned long long)addr, v);
#else
    unsigned int* w = (unsigned int*)addr;
    unsigned int old = *w, assumed;
    do {
        assumed = old;
        float fl = bs2f((unsigned short)(assumed & 0xffff)) + lo;
        float fh = bs2f((unsigned short)(assumed >> 16)) + hi;
        unsigned int nv = ((unsigned int)(unsigned short)f2bs(fh) << 16) |
                          (unsigned short)f2bs(fl);
        old = atomicCAS(w, assumed, nv);
    } while (old != assumed);
#endif
}

// flush one merged run: 8 accumulated features/lane -> 4 pk atomics/lane.
// Run boundaries are quad-uniform so the lane^1 shuffles pair active lanes.
__device__ __forceinline__ void flush_pk(short* aggrow, const float* accum, int col) {
    bool even = ((col & 1) == 0);
#pragma unroll
    for (int q = 0; q < 4; q++) {
        float a = accum[2 * q], b = accum[2 * q + 1];
        float pa = __shfl_xor(a, 1);   // feature (2q)*16 + (col^1)
        float pb = __shfl_xor(b, 1);
        int nbase = even ? (2 * q) * 16 + col : (2 * q + 1) * 16 + (col - 1);
        float lo = even ? a : pb;
        float hi = even ? pa : b;
        atomic_pk_add_bf16(aggrow + nbase, lo, hi);
    }
}

// ---------------------------------------------------------------------------
// Weight prep: dst[b][c][r] = bf16(src[b][r][c])
// ---------------------------------------------------------------------------
__global__ void transpose_cvt(const float* __restrict__ src, short* __restrict__ dst,
                              int R, int C, int total) {
    int t = blockIdx.x * blockDim.x + threadIdx.x;
    if (t >= total) return;
    int rc = R * C;
    int b = t / rc;
    int rem = t - b * rc;
    int c = rem / R;
    int r = rem - c * R;
    dst[t] = f2bs(src[(size_t)b * rc + (size_t)r * C + c]);
}

// ---------------------------------------------------------------------------
// Edge prep: distances + per-atom histogram. 4 edges/thread for MLP.
// ---------------------------------------------------------------------------
__global__ void edge_prep4(const float* __restrict__ pos,
                           const int* __restrict__ idx_i,
                           const int* __restrict__ idx_j,
                           float* __restrict__ d_ij,
                           int* __restrict__ hist,
                           int E) {
    int b0 = blockIdx.x * 1024 + threadIdx.x;
    int ia[4], ib[4];
    bool val[4];
#pragma unroll
    for (int k = 0; k < 4; k++) {
        int e = b0 + k * 256;
        val[k] = (e < E);
        ia[k] = val[k] ? idx_i[e] : 0;
        ib[k] = val[k] ? idx_j[e] : 0;
    }
    float ax[4], ay[4], az[4], bx[4], by[4], bz[4];
#pragma unroll
    for (int k = 0; k < 4; k++) {
        const float* pa = pos + ia[k] * 3;
        ax[k] = pa[0]; ay[k] = pa[1]; az[k] = pa[2];
    }
#pragma unroll
    for (int k = 0; k < 4; k++) {
        const float* pb = pos + ib[k] * 3;
        bx[k] = pb[0]; by[k] = pb[1]; bz[k] = pb[2];
    }
#pragma unroll
    for (int k = 0; k < 4; k++) {
        if (!val[k]) continue;
        float dx = ax[k] - bx[k], dy = ay[k] - by[k], dz = az[k] - bz[k];
        float d = sqrtf(dx * dx + dy * dy + dz * dz);
        d_ij[b0 + k * 256] = d;
        if (d < CUTOFF_F) atomicAdd(&hist[ia[k]], 1);
    }
}

// ---------------------------------------------------------------------------
// Single-block exclusive scan of hist[N] -> cursor[N]  (1024 threads).
// ---------------------------------------------------------------------------
__global__ __launch_bounds__(1024) void scan_hist(const int* __restrict__ hist,
                                                  int* __restrict__ cursor, int N) {
    __shared__ int part[1024];
    int t = threadIdx.x;
    int chunk = (N + 1023) / 1024;
    int lo = t * chunk;
    int hi = min(lo + chunk, N);
    int s = 0;
    for (int i = lo; i < hi; i++) s += hist[i];
    part[t] = s;
    __syncthreads();
    for (int d = 1; d < 1024; d <<= 1) {
        int v = (t >= d) ? part[t - d] : 0;
        __syncthreads();
        part[t] += v;
        __syncthreads();
    }
    int run = (t == 0) ? 0 : part[t - 1];
    for (int i = lo; i < hi; i++) {
        cursor[i] = run;
        run += hist[i];
    }
}

// ---------------------------------------------------------------------------
// Scatter active edges into idx_i-grouped order. 4 edges/thread for MLP.
// Computes rcut for active edges only. After: cursor[a] == end of range.
// ---------------------------------------------------------------------------
__global__ void scatter_sorted4(const float* __restrict__ d_ij,
                                const int* __restrict__ idx_i,
                                const int* __restrict__ idx_j,
                                const int* __restrict__ edge_attr,
                                int* __restrict__ cursor,
                                float4* __restrict__ edata,
                                int* __restrict__ sIarr,
                                int* __restrict__ sJarr, int E) {
    int b0 = blockIdx.x * 1024 + threadIdx.x;
    float d[4]; int ii[4], jj[4], at[4]; bool act[4];
#pragma unroll
    for (int k = 0; k < 4; k++) {
        int e = b0 + k * 256;
        bool v = (e < E);
        d[k] = v ? d_ij[e] : 1e9f;
        act[k] = (d[k] < CUTOFF_F);
        ii[k] = act[k] ? idx_i[e] : 0;
        jj[k] = act[k] ? idx_j[e] : 0;
        at[k] = act[k] ? edge_attr[e] : 0;
    }
    int p[4];
#pragma unroll
    for (int k = 0; k < 4; k++)
        if (act[k]) p[k] = atomicAdd(&cursor[ii[k]], 1);
#pragma unroll
    for (int k = 0; k < 4; k++) {
        if (!act[k]) continue;
        float4 v;
        v.x = d[k];
        v.y = 0.5f * (__cosf(d[k] * PI_OVER_CUT) + 1.0f);
        v.z = __int_as_float(jj[k]);
        v.w = __int_as_float(at[k]);
        edata[p[k]] = v;
        sIarr[p[k]] = ii[k];
        sJarr[p[k]] = jj[k];
    }
}

// ---------------------------------------------------------------------------
// x = ele_emb[z] + res_emb[z_res]
// ---------------------------------------------------------------------------
__global__ void atom_embed(const int* __restrict__ z,
                           const int* __restrict__ z_res,
                           const float* __restrict__ ele_emb,
                           const float* __restrict__ res_emb,
                           float* __restrict__ x, int N) {
    int t = blockIdx.x * blockDim.x + threadIdx.x;
    if (t >= N * NB) return;
    int n = t >> 7, c = t & 127;
    x[t] = ele_emb[z[n] * NB + c] + res_emb[z_res[n] * NB + c];
}

// ---------------------------------------------------------------------------
// xf(bf16, permuted cols) = in(fp32) @ W  via MFMA. First-iteration in2f.
// ---------------------------------------------------------------------------
__global__ __launch_bounds__(256, 4) void node_in2f_mfma(
    const float* __restrict__ x, const short* __restrict__ WT,
    short* __restrict__ xf, int N) {
    __shared__ __align__(16) short XA[64 * HPAD];
    int a0 = blockIdx.x * 64;
    int t = threadIdx.x;
#pragma unroll
    for (int c = 0; c < 4; c++) {
        int chunk = t + c * 256;
        int row = chunk >> 4;
        int col = (chunk & 15) * 8;
        short v[8];
        if (a0 + row < N) {
            const float* src = x + (size_t)(a0 + row) * NB + col;
            float4 f0 = *(const float4*)src;
            float4 f1 = *(const float4*)(src + 4);
            v[0] = f2bs(f0.x); v[1] = f2bs(f0.y); v[2] = f2bs(f0.z); v[3] = f2bs(f0.w);
            v[4] = f2bs(f1.x); v[5] = f2bs(f1.y); v[6] = f2bs(f1.z); v[7] = f2bs(f1.w);
        } else {
#pragma unroll
            for (int j = 0; j < 8; j++) v[j] = 0;
        }
        *(bf16x8*)&XA[row * HPAD + col] = *(bf16x8*)v;
    }
    __syncthreads();

    int wid = t >> 6, lane = t & 63;
    int quad = lane >> 4, col = lane & 15;
    int mrow = wid * 16 + col;

    f32x4 acc[8] = {};
#pragma unroll
    for (int kt = 0; kt < 4; kt++) {
        bf16x8 a = *(bf16x8*)&XA[mrow * HPAD + kt * 32 + quad * 8];
#pragma unroll
        for (int nt = 0; nt < 8; nt++) {
            bf16x8 b = *(const bf16x8*)&WT[(nt * 16 + col) * NB + kt * 32 + quad * 8];
            acc[nt] = __builtin_amdgcn_mfma_f32_16x16x32_bf16(a, b, acc[nt], 0, 0, 0);
        }
    }
#pragma unroll
    for (int nt = 0; nt < 8; nt++) {
        int cst = col * 8 + nt;   // permuted storage col
#pragma unroll
        for (int r = 0; r < 4; r++) {
            int m = wid * 16 + quad * 4 + r;
            if (a0 + m < N) xf[(size_t)(a0 + m) * NB + cst] = f2bs(acc[nt][r]);
        }
    }
}

// ---------------------------------------------------------------------------
// Fused: v = ssp(agg@W1+b1)@W2+b2 ; x += v ; xf_next(bf16, permuted) = x @ Wn
// agg is bf16 in ORIGINAL feature order. After staging agg, this kernel
// re-zeroes its agg rows (replaces the inter-iteration memset).
// ---------------------------------------------------------------------------
__global__ __launch_bounds__(256, 4) void node_fused_mfma(
    short* __restrict__ agg,
    const short* __restrict__ W1T, const float* __restrict__ b1,
    const short* __restrict__ W2T, const float* __restrict__ b2,
    const short* __restrict__ WnT,
    float* __restrict__ x, short* __restrict__ xf, int N) {
    __shared__ __align__(16) short XA[64 * HPAD];
    __shared__ __align__(16) short H[64 * HPAD];
    int a0 = blockIdx.x * 64;
    int t = threadIdx.x;
#pragma unroll
    for (int c = 0; c < 4; c++) {
        int chunk = t + c * 256;
        int row = chunk >> 4;
        int col = (chunk & 15) * 8;
        bf16x8 v = {0, 0, 0, 0, 0, 0, 0, 0};
        if (a0 + row < N) {
            short* src = agg + (size_t)(a0 + row) * NB + col;
            v = *(const bf16x8*)src;
            *(bf16x8*)src = (bf16x8){0, 0, 0, 0, 0, 0, 0, 0};  // re-zero for next iter
        }
        *(bf16x8*)&XA[row * HPAD + col] = v;
    }
    __syncthreads();

    int wid = t >> 6, lane = t & 63;
    int quad = lane >> 4, col = lane & 15;
    int mrow = wid * 16 + col;

    // GEMM1 + ssp -> H
    {
        f32x4 acc[8] = {};
#pragma unroll
        for (int kt = 0; kt < 4; kt++) {
            bf16x8 a = *(bf16x8*)&XA[mrow * HPAD + kt * 32 + quad * 8];
#pragma unroll
            for (int nt = 0; nt < 8; nt++) {
                bf16x8 b = *(const bf16x8*)&W1T[(nt * 16 + col) * NB + kt * 32 + quad * 8];
                acc[nt] = __builtin_amdgcn_mfma_f32_16x16x32_bf16(a, b, acc[nt], 0, 0, 0);
            }
        }
#pragma unroll
        for (int nt = 0; nt < 8; nt++) {
            int n = nt * 16 + col;
            float bias = b1[n];
#pragma unroll
            for (int r = 0; r < 4; r++) {
                int m = wid * 16 + quad * 4 + r;
                H[m * HPAD + n] = f2bs(ssp_f(acc[nt][r] + bias));
            }
        }
    }
    __syncthreads();

    // GEMM2 + residual: x_new -> global fp32 + XA bf16 (reuse)
    {
        f32x4 acc[8] = {};
#pragma unroll
        for (int kt = 0; kt < 4; kt++) {
            bf16x8 a = *(bf16x8*)&H[mrow * HPAD + kt * 32 + quad * 8];
#pragma unroll
            for (int nt = 0; nt < 8; nt++) {
                bf16x8 b = *(const bf16x8*)&W2T[(nt * 16 + col) * NB + kt * 32 + quad * 8];
                acc[nt] = __builtin_amdgcn_mfma_f32_16x16x32_bf16(a, b, acc[nt], 0, 0, 0);
            }
        }
#pragma unroll
        for (int nt = 0; nt < 8; nt++) {
            int n = nt * 16 + col;
            float bias = b2[n];
#pragma unroll
            for (int r = 0; r < 4; r++) {
                int m = wid * 16 + quad * 4 + r;
                float xn = 0.0f;
                if (a0 + m < N) {
                    size_t o = (size_t)(a0 + m) * NB + n;
                    xn = x[o] + acc[nt][r] + bias;
                    x[o] = xn;
                }
                XA[m * HPAD + n] = f2bs(xn);
            }
        }
    }
    __syncthreads();

    // GEMM3: xf = x_new @ Wn  (bf16 out, permuted storage cols)
    {
        f32x4 acc[8] = {};
#pragma unroll
        for (int kt = 0; kt < 4; kt++) {
            bf16x8 a = *(bf16x8*)&XA[mrow * HPAD + kt * 32 + quad * 8];
#pragma unroll
            for (int nt = 0; nt < 8; nt++) {
                bf16x8 b = *(const bf16x8*)&WnT[(nt * 16 + col) * NB + kt * 32 + quad * 8];
                acc[nt] = __builtin_amdgcn_mfma_f32_16x16x32_bf16(a, b, acc[nt], 0, 0, 0);
            }
        }
#pragma unroll
        for (int nt = 0; nt < 8; nt++) {
            int cst = col * 8 + nt;
#pragma unroll
            for (int r = 0; r < 4; r++) {
                int m = wid * 16 + quad * 4 + r;
                if (a0 + m < N) xf[(size_t)(a0 + m) * NB + cst] = f2bs(acc[nt][r]);
            }
        }
    }
}

// ---------------------------------------------------------------------------
// Last iteration fused with head: v = ssp(agg@W1+b1)@W2+b2 ; xn = x + v ;
// h = silu(xn/||xn||) ; silu(h@hW1+hb1)@hW2 ; segment-sum by batch.
// ---------------------------------------------------------------------------
__global__ __launch_bounds__(256, 4) void node_out_head_mfma(
    const short* __restrict__ agg,
    const short* __restrict__ W1T, const float* __restrict__ b1,
    const short* __restrict__ W2T, const float* __restrict__ b2,
    const float* __restrict__ x, const int* __restrict__ batch,
    const short* __restrict__ hW1T, const float* __restrict__ hb1,
    const float* __restrict__ hW2,
    float* __restrict__ out, int N) {
    __shared__ __align__(16) short XA[64 * HPAD];
    __shared__ __align__(16) short H[64 * HPAD];
    __shared__ int sbat[64];
    __shared__ float rowval[64];
    int a0 = blockIdx.x * 64;
    int t = threadIdx.x;

    if (t < 64) sbat[t] = (a0 + t < N) ? batch[a0 + t] : -1;
#pragma unroll
    for (int c = 0; c < 4; c++) {
        int chunk = t + c * 256;
        int row = chunk >> 4;
        int col = (chunk & 15) * 8;
        bf16x8 v = {0, 0, 0, 0, 0, 0, 0, 0};
        if (a0 + row < N) v = *(const bf16x8*)&agg[(size_t)(a0 + row) * NB + col];
        *(bf16x8*)&XA[row * HPAD + col] = v;
    }
    __syncthreads();

    int wid = t >> 6, lane = t & 63;
    int quad = lane >> 4, col = lane & 15;
    int mrow = wid * 16 + col;

    // GEMM1 + ssp -> H
    {
        f32x4 acc[8] = {};
#pragma unroll
        for (int kt = 0; kt < 4; kt++) {
            bf16x8 a = *(bf16x8*)&XA[mrow * HPAD + kt * 32 + quad * 8];
#pragma unroll
            for (int nt = 0; nt < 8; nt++) {
                bf16x8 b = *(const bf16x8*)&W1T[(nt * 16 + col) * NB + kt * 32 + quad * 8];
                acc[nt] = __builtin_amdgcn_mfma_f32_16x16x32_bf16(a, b, acc[nt], 0, 0, 0);
            }
        }
#pragma unroll
        for (int nt = 0; nt < 8; nt++) {
            int n = nt * 16 + col;
            float bias = b1[n];
#pragma unroll
            for (int r = 0; r < 4; r++) {
                int m = wid * 16 + quad * 4 + r;
                H[m * HPAD + n] = f2bs(ssp_f(acc[nt][r] + bias));
            }
        }
    }
    __syncthreads();

    // GEMM2 + residual in registers; row sums of squares via 16-lane shuffle
    float xnv[8][4];
    float ssq[4] = {0.f, 0.f, 0.f, 0.f};
    {
        f32x4 acc[8] = {};
#pragma unroll
        for (int kt = 0; kt < 4; kt++) {
            bf16x8 a = *(bf16x8*)&H[mrow * HPAD + kt * 32 + quad * 8];
#pragma unroll
            for (int nt = 0; nt < 8; nt++) {
                bf16x8 b = *(const bf16x8*)&W2T[(nt * 16 + col) * NB + kt * 32 + quad * 8];
                acc[nt] = __builtin_amdgcn_mfma_f32_16x16x32_bf16(a, b, acc[nt], 0, 0, 0);
            }
        }
#pragma unroll
        for (int nt = 0; nt < 8; nt++) {
            int n = nt * 16 + col;
            float bias = b2[n];
#pragma unroll
            for (int r = 0; r < 4; r++) {
                int m = wid * 16 + quad * 4 + r;
                float xn = 0.0f;
                if (a0 + m < N) xn = x[(size_t)(a0 + m) * NB + n] + acc[nt][r] + bias;
                xnv[nt][r] = xn;
                ssq[r] += xn * xn;
            }
        }
    }
#pragma unroll
    for (int r = 0; r < 4; r++) {
#pragma unroll
        for (int m = 1; m < 16; m <<= 1) ssq[r] += __shfl_xor(ssq[r], m);
    }
    float inv[4];
#pragma unroll
    for (int r = 0; r < 4; r++) inv[r] = 1.0f / fmaxf(sqrtf(ssq[r]), 1e-12f);
    __syncthreads();
#pragma unroll
    for (int nt = 0; nt < 8; nt++) {
        int n = nt * 16 + col;
#pragma unroll
        for (int r = 0; r < 4; r++) {
            int m = wid * 16 + quad * 4 + r;
            XA[m * HPAD + n] = f2bs(silu_f(xnv[nt][r] * inv[r]));
        }
    }
    __syncthreads();

    // head GEMM: silu(h@hW1+hb1) dot hW2 per row
    f32x4 acc[8] = {};
#pragma unroll
    for (int kt = 0; kt < 4; kt++) {
        bf16x8 a = *(bf16x8*)&XA[mrow * HPAD + kt * 32 + quad * 8];
#pragma unroll
        for (int nt = 0; nt < 8; nt++) {
            bf16x8 b = *(const bf16x8*)&hW1T[(nt * 16 + col) * NB + kt * 32 + quad * 8];
            acc[nt] = __builtin_amdgcn_mfma_f32_16x16x32_bf16(a, b, acc[nt], 0, 0, 0);
        }
    }
    float partial[4] = {0.f, 0.f, 0.f, 0.f};
#pragma unroll
    for (int nt = 0; nt < 8; nt++) {
        int n = nt * 16 + col;
        float bias = hb1[n];
        float w2 = hW2[n];
#pragma unroll
        for (int r = 0; r < 4; r++) partial[r] += silu_f(acc[nt][r] + bias) * w2;
    }
#pragma unroll
    for (int r = 0; r < 4; r++) {
#pragma unroll
        for (int d = 1; d < 16; d <<= 1) partial[r] += __shfl_xor(partial[r], d);
    }
    if (col == 0) {
#pragma unroll
        for (int r = 0; r < 4; r++) rowval[wid * 16 + quad * 4 + r] = partial[r];
    }
    __syncthreads();

    if (t < 64) {
        int b = sbat[t];
        bool headf = (b >= 0) && (t == 0 || sbat[t - 1] != b);
        if (headf) {
            float s = 0.0f;
            int rr = t;
            while (rr < 64 && sbat[rr] == b) { s += rowval[rr]; rr++; }
            atomicAdd(&out[b], s);
        }
    }
}

// ---------------------------------------------------------------------------
// SPLIT KERNEL A: per-edge filter MLP only (barrier-free, r19 structure).
// Handles edges [ebase + blockIdx*64, ...). Writes Wij*rcut as bf16 in the
// PERMUTED layout at Wbuf[(e-ebase)*NB] -> coalesced 16B/lane stores.
// ---------------------------------------------------------------------------
__global__ __launch_bounds__(256, 4) void edge_filter_mfma(
    const float4* __restrict__ edata,
    const int* __restrict__ rowend, int natoms,
    const float* __restrict__ edge_emb,
    const short* __restrict__ W1T, const float* __restrict__ b1,
    const short* __restrict__ W2T, const float* __restrict__ b2,
    short* __restrict__ Wbuf, int ebase) {
    __shared__ __align__(16) short fA[64 * EPAD];
    __shared__ __align__(16) short H[64 * HPAD];

    int t = threadIdx.x;
    int wid = t >> 6, lane = t & 63;
    int quad = lane >> 4, col = lane & 15;
    int base = ebase + blockIdx.x * 64;
    int wbase = base + wid * 16;        // this wave's 16-edge window
    int el16 = lane & 15;

    float4 ed = edata[wbase + el16];
    int cnt = rowend[natoms - 1];
    if (base >= cnt) return;

    bool act = (wbase + el16) < cnt;
    float dv  = act ? ed.x : 1e9f;
    float rcv = act ? ed.y : 0.0f;
    int   atv = act ? __float_as_int(ed.w) : 0;

    // stage A: f_ij tile (RBF + edge_emb), bf16 (wave-local rows)
    {
        int elA = lane >> 2;
        int r0 = (lane & 3) * 8;
        float d  = __shfl(dv, elA);
        int   at = __shfl(atv, elA);
        const float* em = edge_emb + at * NR + r0;
        short v[8];
#pragma unroll
        for (int j = 0; j < 8; j++) {
            float off = (float)(r0 + j) * RBF_STEP;
            float dd = d - off;
            v[j] = f2bs(__expf(RBF_COEFF * dd * dd) + em[j]);
        }
        *(bf16x8*)&fA[(wid * 16 + elA) * EPAD + r0] = *(bf16x8*)v;
    }

    asm volatile("s_waitcnt lgkmcnt(0)" ::: "memory");
    __builtin_amdgcn_sched_barrier(0);

    int mrow = wid * 16 + col;

    // GEMM1: hidden = f_ij @ W1 (K=32) ; ssp -> H
    {
        bf16x8 a1 = *(bf16x8*)&fA[mrow * EPAD + quad * 8];
        f32x4 acc[8];
#pragma unroll
        for (int nt = 0; nt < 8; nt++) {
            bf16x8 b = *(const bf16x8*)&W1T[(nt * 16 + col) * NR + quad * 8];
            acc[nt] = __builtin_amdgcn_mfma_f32_16x16x32_bf16(a1, b, (f32x4){0.f, 0.f, 0.f, 0.f}, 0, 0, 0);
        }
#pragma unroll
        for (int nt = 0; nt < 8; nt++) {
            int n = nt * 16 + col;
            float bias = b1[n];
#pragma unroll
            for (int r = 0; r < 4; r++) {
                int m = wid * 16 + quad * 4 + r;
                H[m * HPAD + n] = f2bs(ssp_f(acc[nt][r] + bias));
            }
        }
    }

    asm volatile("s_waitcnt lgkmcnt(0)" ::: "memory");
    __builtin_amdgcn_sched_barrier(0);

    // GEMM2: Wij = hidden @ W2 (K=128)
    f32x4 acc2[8] = {};
#pragma unroll
    for (int kt = 0; kt < 4; kt++) {
        bf16x8 a = *(bf16x8*)&H[mrow * HPAD + kt * 32 + quad * 8];
#pragma unroll
        for (int nt = 0; nt < 8; nt++) {
            bf16x8 b = *(const bf16x8*)&W2T[(nt * 16 + col) * NB + kt * 32 + quad * 8];
            acc2[nt] = __builtin_amdgcn_mfma_f32_16x16x32_bf16(a, b, acc2[nt], 0, 0, 0);
        }
    }

    // epilogue: w = (acc2 + b2) * rc ; store 16B/edge/lane (coalesced)
    float b2v[8];
#pragma unroll
    for (int nt = 0; nt < 8; nt++) b2v[nt] = b2[nt * 16 + col];
#pragma unroll
    for (int r = 0; r < 4; r++) {
        int m = quad * 4 + r;               // wave-local edge
        int e = wbase + m;                  // global sorted edge id
        float rc = __shfl(rcv, m);
        short v[8];
#pragma unroll
        for (int nt = 0; nt < 8; nt++) v[nt] = f2bs((acc2[nt][r] + b2v[nt]) * rc);
        if (e < cnt) *(bf16x8*)&Wbuf[(size_t)(e - ebase) * NB + col * 8] = *(bf16x8*)v;
    }
}

// ---------------------------------------------------------------------------
// SPLIT KERNEL B: gather + multiply + scatter only. No LDS, no MFMA, no
// barriers. Handles edges [ebase + blockIdx*256, ...); quad owns 16
// CONTIGUOUS edges (4x4 iters, cross-iter run merge).
// ---------------------------------------------------------------------------
__global__ __launch_bounds__(256, 8) void edge_scatter(
    const int* __restrict__ sIarr, const int* __restrict__ sJarr,
    const int* __restrict__ rowend, int natoms,
    const short* __restrict__ Wbuf, const short* __restrict__ xf,
    short* __restrict__ agg, int ebase) {
    int cnt = rowend[natoms - 1];
    int t = threadIdx.x;
    int wid = t >> 6, lane = t & 63;
    int quad = lane >> 4, col = lane & 15;
    int base = ebase + blockIdx.x * 256 + wid * 64;   // this wave's 64 edges
    if (base >= cnt) return;
    int qbase = base + quad * 16;             // quad's 16 contiguous edges

    // lane col c holds the record of edge qbase+c
    int eRec = qbase + col;
    bool vRec = eRec < cnt;
    int iiR = vRec ? sIarr[eRec] : 0;
    int jjR = vRec ? sJarr[eRec] : 0;

    const unsigned short* xg = (const unsigned short*)xf;
    const unsigned short* wg = (const unsigned short*)Wbuf;

    int cur = __shfl(iiR, quad * 16);         // first edge's atom
    float accum[8] = {0.f, 0.f, 0.f, 0.f, 0.f, 0.f, 0.f, 0.f};
#pragma unroll
    for (int it = 0; it < 4; it++) {
        bf16x8 wv[4], xv[4];
        int ii4[4];
#pragma unroll
        for (int r = 0; r < 4; r++) {
            int l = it * 4 + r;
            int e = qbase + l;
            int jj = __shfl(jjR, quad * 16 + l);
            ii4[r] = __shfl(iiR, quad * 16 + l);
            if (e < cnt) {                     // quad-uniform
                wv[r] = *(const bf16x8*)&wg[(size_t)(e - ebase) * NB + col * 8];
                xv[r] = *(const bf16x8*)&xg[(size_t)jj * NB + col * 8];
            } else {
                wv[r] = (bf16x8){0, 0, 0, 0, 0, 0, 0, 0};
                xv[r] = (bf16x8){0, 0, 0, 0, 0, 0, 0, 0};
            }
        }
#pragma unroll
        for (int r = 0; r < 4; r++) {
            if (ii4[r] != cur) {               // quad-uniform branch
                flush_pk(agg + (size_t)cur * NB, accum, col);
#pragma unroll
                for (int k = 0; k < 8; k++) accum[k] = 0.f;
                cur = ii4[r];
            }
#pragma unroll
            for (int nt = 0; nt < 8; nt++)
                accum[nt] = fmaf(bs2f((unsigned short)wv[r][nt]),
                                 bs2f((unsigned short)xv[r][nt]), accum[nt]);
        }
    }
    flush_pk(agg + (size_t)cur * NB, accum, col);
}

// ---------------------------------------------------------------------------
// Monolithic fallback (r19) — used if workspace can't hold even a min chunk.
// ---------------------------------------------------------------------------
__global__ __launch_bounds__(256, 4) void edge_fused_mfma(
    const float4* __restrict__ edata, const int* __restrict__ sIarr,
    const int* __restrict__ rowend, int natoms,
    const float* __restrict__ edge_emb,
    const short* __restrict__ W1T, const float* __restrict__ b1,
    const short* __restrict__ W2T, const float* __restrict__ b2,
    const short* __restrict__ xf, short* __restrict__ agg) {
    __shared__ __align__(16) short fA[64 * EPAD];
    __shared__ __align__(16) short H[64 * HPAD];

    int t = threadIdx.x;
    int wid = t >> 6, lane = t & 63;
    int quad = lane >> 4, col = lane & 15;
    int base = blockIdx.x * 64;
    int wbase = base + wid * 16;
    int el16 = lane & 15;

    float4 ed = edata[wbase + el16];
    int sIv0 = sIarr[wbase + el16];
    int cnt = rowend[natoms - 1];
    if (base >= cnt) return;

    bool act = (wbase + el16) < cnt;
    float dv  = act ? ed.x : 1e9f;
    float rcv = act ? ed.y : 0.0f;
    int   jjv = act ? __float_as_int(ed.z) : 0;
    int   atv = act ? __float_as_int(ed.w) : 0;
    int   iiv = act ? sIv0 : 0;

    {
        int elA = lane >> 2;
        int r0 = (lane & 3) * 8;
        float d  = __shfl(dv, elA);
        int   at = __shfl(atv, elA);
        const float* em = edge_emb + at * NR + r0;
        short v[8];
#pragma unroll
        for (int j = 0; j < 8; j++) {
            float off = (float)(r0 + j) * RBF_STEP;
            float dd = d - off;
            v[j] = f2bs(__expf(RBF_COEFF * dd * dd) + em[j]);
        }
        *(bf16x8*)&fA[(wid * 16 + elA) * EPAD + r0] = *(bf16x8*)v;
    }

    int e0l = quad * 4;
    bf16x8 xv[4];
    const unsigned short* xg = (const unsigned short*)xf;
#pragma unroll
    for (int r = 0; r < 4; r++) {
        int jj = __shfl(jjv, e0l + r);
        xv[r] = *(const bf16x8*)&xg[(size_t)jj * NB + col * 8];
    }

    asm volatile("s_waitcnt lgkmcnt(0)" ::: "memory");
    __builtin_amdgcn_sched_barrier(0);

    int mrow = wid * 16 + col;

    {
        bf16x8 a1 = *(bf16x8*)&fA[mrow * EPAD + quad * 8];
        f32x4 acc[8];
#pragma unroll
        for (int nt = 0; nt < 8; nt++) {
            bf16x8 b = *(const bf16x8*)&W1T[(nt * 16 + col) * NR + quad * 8];
            acc[nt] = __builtin_amdgcn_mfma_f32_16x16x32_bf16(a1, b, (f32x4){0.f, 0.f, 0.f, 0.f}, 0, 0, 0);
        }
#pragma unroll
        for (int nt = 0; nt < 8; nt++) {
            int n = nt * 16 + col;
            float bias = b1[n];
#pragma unroll
            for (int r = 0; r < 4; r++) {
                int m = wid * 16 + quad * 4 + r;
                H[m * HPAD + n] = f2bs(ssp_f(acc[nt][r] + bias));
            }
        }
    }

    asm volatile("s_waitcnt lgkmcnt(0)" ::: "memory");
    __builtin_amdgcn_sched_barrier(0);

    f32x4 acc2[8] = {};
#pragma unroll
    for (int kt = 0; kt < 4; kt++) {
        bf16x8 a = *(bf16x8*)&H[mrow * HPAD + kt * 32 + quad * 8];
#pragma unroll
        for (int nt = 0; nt < 8; nt++) {
            bf16x8 b = *(const bf16x8*)&W2T[(nt * 16 + col) * NB + kt * 32 + quad * 8];
            acc2[nt] = __builtin_amdgcn_mfma_f32_16x16x32_bf16(a, b, acc2[nt], 0, 0, 0);
        }
    }

    float b2v[8];
#pragma unroll
    for (int nt = 0; nt < 8; nt++) b2v[nt] = b2[nt * 16 + col];

    int cur = __shfl(iiv, e0l);
    float accum[8] = {0.f, 0.f, 0.f, 0.f, 0.f, 0.f, 0.f, 0.f};
#pragma unroll
    for (int r = 0; r < 4; r++) {
        int ii = __shfl(iiv, e0l + r);
        float rc = __shfl(rcv, e0l + r);
        if (ii != cur) {
            flush_pk(agg + (size_t)cur * NB, accum, col);
#pragma unroll
            for (int nt = 0; nt < 8; nt++) accum[nt] = 0.f;
            cur = ii;
        }
#pragma unroll
        for (int nt = 0; nt < 8; nt++) {
            float w = (acc2[nt][r] + b2v[nt]) * rc;
            accum[nt] = fmaf(w, bs2f((unsigned short)xv[r][nt]), accum[nt]);
        }
    }
    flush_pk(agg + (size_t)cur * NB, accum, col);
}

// ---------------------------------------------------------------------------
extern "C" void kernel_launch(void* const* d_in, const int* in_sizes, int n_in,
                              void* d_out, int out_size, void* d_ws, size_t ws_size,
                              hipStream_t stream) {
    const int*   z        = (const int*)d_in[0];
    const int*   z_res    = (const int*)d_in[1];
    const float* pos      = (const float*)d_in[2];
    const int*   idx_i    = (const int*)d_in[3];
    const int*   idx_j    = (const int*)d_in[4];
    const int*   edge_attr= (const int*)d_in[5];
    const int*   batch    = (const int*)d_in[6];
    const float* ele_emb  = (const float*)d_in[7];
    const float* res_emb  = (const float*)d_in[8];
    const float* edge_emb = (const float*)d_in[9];
    const float* in2f_W   = (const float*)d_in[10];
    const float* filt_W1  = (const float*)d_in[11];
    const float* filt_b1  = (const float*)d_in[12];
    const float* filt_W2  = (const float*)d_in[13];
    const float* filt_b2  = (const float*)d_in[14];
    const float* f2out_W1 = (const float*)d_in[15];
    const float* f2out_b1 = (const float*)d_in[16];
    const float* f2out_W2 = (const float*)d_in[17];
    const float* f2out_b2 = (const float*)d_in[18];
    const float* head_W1  = (const float*)d_in[19];
    const float* head_b1  = (const float*)d_in[20];
    const float* head_W2  = (const float*)d_in[21];

    const int N = in_sizes[0];
    const int E = in_sizes[3];

    char* p = (char*)d_ws;
    size_t off = 0;
    auto carve = [&](size_t bytes) -> void* {
        void* q = p + off;
        off = (off + bytes + 255) & ~(size_t)255;
        return q;
    };
    float*  d_d      = (float*)carve((size_t)E * 4);
    float4* edata    = (float4*)carve((size_t)E * 16);
    int*    sIarr    = (int*)carve((size_t)E * 4);
    int*    sJarr    = (int*)carve((size_t)E * 4);
    int*    hist     = (int*)carve((size_t)N * 4);
    int*    cursor   = (int*)carve((size_t)N * 4);
    float*  x_buf    = (float*)carve((size_t)N * NB * 4);
    short*  xf_buf   = (short*)carve((size_t)N * NB * 2);
    short*  agg      = (short*)carve((size_t)N * NB * 2);
    short*  in2f_WT  = (short*)carve((size_t)6 * NB * NB * 2);
    short*  fW1T     = (short*)carve((size_t)6 * NR * NB * 2);
    short*  fW2T     = (short*)carve((size_t)6 * NB * NB * 2);
    short*  oW1T     = (short*)carve((size_t)6 * NB * NB * 2);
    short*  oW2T     = (short*)carve((size_t)6 * NB * NB * 2);
    short*  hW1T     = (short*)carve((size_t)NB * NB * 2);
    // Wbuf = whatever remains; chunk the edge loop to fit.
    short*  Wbuf     = (short*)(p + off);
    size_t  rem      = (ws_size > off) ? (ws_size - off) : 0;
    long long maxEd  = (long long)(rem / ((size_t)NB * 2));
    int chunkE = (int)((maxEd > (long long)E) ? E : maxEd);
    chunkE &= ~1023;                       // multiple of 1024 (>= block tiles)
    bool split = (chunkE >= 65536);        // need >= 64K-edge chunks (16MB)

    // weight prep (bf16 transposed)
    {
        int tot = 6 * NB * NB;
        transpose_cvt<<<(tot + 255) / 256, 256, 0, stream>>>(in2f_W, in2f_WT, NB, NB, tot);
        transpose_cvt<<<(tot + 255) / 256, 256, 0, stream>>>(filt_W2, fW2T, NB, NB, tot);
        transpose_cvt<<<(tot + 255) / 256, 256, 0, stream>>>(f2out_W1, oW1T, NB, NB, tot);
        transpose_cvt<<<(tot + 255) / 256, 256, 0, stream>>>(f2out_W2, oW2T, NB, NB, tot);
        int tot1 = 6 * NR * NB;
        transpose_cvt<<<(tot1 + 255) / 256, 256, 0, stream>>>(filt_W1, fW1T, NR, NB, tot1);
        int tot2 = NB * NB;
        transpose_cvt<<<(tot2 + 255) / 256, 256, 0, stream>>>(head_W1, hW1T, NB, NB, tot2);
    }

    // edge prep + idx_i-grouped sort with packed records
    hipMemsetAsync(hist, 0, (size_t)N * 4, stream);
    int nblk_e4 = (E + 1023) / 1024;
    edge_prep4<<<nblk_e4, 256, 0, stream>>>(pos, idx_i, idx_j, d_d, hist, E);
    scan_hist<<<1, 1024, 0, stream>>>(hist, cursor, N);
    scatter_sorted4<<<nblk_e4, 256, 0, stream>>>(d_d, idx_i, idx_j, edge_attr,
                                                 cursor, edata, sIarr, sJarr, E);
    // cursor[a] is now the END of atom a's sorted range; cursor[N-1] = count.

    atom_embed<<<(N * NB + 255) / 256, 256, 0, stream>>>(z, z_res, ele_emb, res_emb, x_buf, N);

    int nblk_atom64 = (N + 63) / 64;
    int nblk_edge = (E + 63) / 64;

    node_in2f_mfma<<<nblk_atom64, 256, 0, stream>>>(x_buf, in2f_WT, xf_buf, N);
    hipMemsetAsync(d_out, 0, (size_t)out_size * sizeof(float), stream);
    hipMemsetAsync(agg, 0, (size_t)N * NB * 2, stream);   // once; node_fused re-zeroes
    for (int i = 0; i < 6; i++) {
        if (split) {
            for (int ebase = 0; ebase < E; ebase += chunkE) {
                int span = (E - ebase < chunkE) ? (E - ebase) : chunkE;
                int nbf = (span + 63) / 64;
                edge_filter_mfma<<<nbf, 256, 0, stream>>>(
                    edata, cursor, N, edge_emb,
                    fW1T + (size_t)i * NR * NB, filt_b1 + (size_t)i * NB,
                    fW2T + (size_t)i * NB * NB, filt_b2 + (size_t)i * NB,
                    Wbuf, ebase);
                int nbs = (span + 255) / 256;
                edge_scatter<<<nbs, 256, 0, stream>>>(
                    sIarr, sJarr, cursor, N, Wbuf, xf_buf, agg, ebase);
            }
        } else {
            edge_fused_mfma<<<nblk_edge, 256, 0, stream>>>(
                edata, sIarr, cursor, N, edge_emb,
                fW1T + (size_t)i * NR * NB, filt_b1 + (size_t)i * NB,
                fW2T + (size_t)i * NB * NB, filt_b2 + (size_t)i * NB,
                xf_buf, agg);
        }
        if (i < 5) {
            node_fused_mfma<<<nblk_atom64, 256, 0, stream>>>(
                agg, oW1T + (size_t)i * NB * NB, f2out_b1 + (size_t)i * NB,
                oW2T + (size_t)i * NB * NB, f2out_b2 + (size_t)i * NB,
                in2f_WT + (size_t)(i + 1) * NB * NB,
                x_buf, xf_buf, N);
        } else {
            node_out_head_mfma<<<nblk_atom64, 256, 0, stream>>>(
                agg, oW1T + (size_t)i * NB * NB, f2out_b1 + (size_t)i * NB,
                oW2T + (size_t)i * NB * NB, f2out_b2 + (size_t)i * NB,
                x_buf, batch, hW1T, head_b1, head_W2,
                (float*)d_out, N);
        }
    }
}

// Round 7
// 2207.678 us; speedup vs baseline: 1.3956x; 1.3956x over previous
//
#include <hip/hip_runtime.h>
#include <hip/hip_bf16.h>
#include <math.h>

#define NB 128
#define NR 32
#define EPAD 40    // fA row stride in shorts
#define HPAD 136   // H/XA row stride in shorts (272B, 16B-aligned rows)
#define SCB 256    // scan blocks

// r22: FAST SCAN + r19 edge kernel. r21's chunked bisection exposed that
// scan_hist (single-block serial scan) costs 160us/launch -- 6.8% of total,
// hidden under the six 225us edge dispatches in every earlier profile. It
// also showed the A/B split halves are each <160us with no superlinear
// interference (A+B ~= monolithic + Wij traffic) -> split reverted.
// r22: 3-kernel multi-block scan (reduce -> scan partials -> expand),
// ~12us, same cursor semantics. Edge path = r19 barrier-free monolithic
// (fastest measured, 226us).
// Falsified: r5 LDS gather staging, r6 owner-computes fusion, r7 permuted
// scatter, r10 pre-barrier gather, r12 analytic A-fragment, r14 2-tile
// pipeline, r16 LDS fp32 agg, r17 bigger tile, r18 cross-quad merge,
// r19 barrier-free (neutral), r20/r21 dispatch split (costs traffic,
// attribution only).

static constexpr float CUTOFF_F    = 10.0f;
static constexpr float RBF_STEP    = 10.0f / 31.0f;
static constexpr float RBF_COEFF   = -4.805f;           // -0.5/(10/31)^2
static constexpr float LOG2_F      = 0.69314718055994531f;
static constexpr float PI_OVER_CUT = 0.314159265358979f;

typedef __attribute__((ext_vector_type(8))) short bf16x8;
typedef __attribute__((ext_vector_type(2))) short bf16x2;
typedef __attribute__((ext_vector_type(4))) float f32x4;

__device__ __forceinline__ short f2bs(float x) {
    __hip_bfloat16 h = __float2bfloat16(x);   // RNE
    return *reinterpret_cast<short*>(&h);
}
__device__ __forceinline__ float bs2f(unsigned short u) {
    unsigned int v = ((unsigned int)u) << 16;
    return __uint_as_float(v);
}
__device__ __forceinline__ float ssp_f(float v) {
    return fmaxf(v, 0.0f) + __logf(1.0f + __expf(-fabsf(v))) - LOG2_F;
}
__device__ __forceinline__ float silu_f(float v) {
    return v / (1.0f + __expf(-v));
}

// packed bf16 atomic add (2 features per op)
__device__ __forceinline__ void atomic_pk_add_bf16(short* addr, float lo, float hi) {
#if __has_builtin(__builtin_amdgcn_global_atomic_fadd_v2bf16)
    typedef bf16x2 __attribute__((address_space(1))) *gptr;
    bf16x2 v;
    v[0] = f2bs(lo);
    v[1] = f2bs(hi);
    __builtin_amdgcn_global_atomic_fadd_v2bf16((gptr)(unsigned long long)addr, v);
#else
    unsigned int* w = (unsigned int*)addr;
    unsigned int old = *w, assumed;
    do {
        assumed = old;
        float fl = bs2f((unsigned short)(assumed & 0xffff)) + lo;
        float fh = bs2f((unsigned short)(assumed >> 16)) + hi;
        unsigned int nv = ((unsigned int)(unsigned short)f2bs(fh) << 16) |
                          (unsigned short)f2bs(fl);
        old = atomicCAS(w, assumed, nv);
    } while (old != assumed);
#endif
}

// flush one merged run: 8 accumulated features/lane -> 4 pk atomics/lane.
// Run boundaries are quad-uniform so the lane^1 shuffles pair active lanes.
__device__ __forceinline__ void flush_pk(short* aggrow, const float* accum, int col) {
    bool even = ((col & 1) == 0);
#pragma unroll
    for (int q = 0; q < 4; q++) {
        float a = accum[2 * q], b = accum[2 * q + 1];
        float pa = __shfl_xor(a, 1);   // feature (2q)*16 + (col^1)
        float pb = __shfl_xor(b, 1);
        int nbase = even ? (2 * q) * 16 + col : (2 * q + 1) * 16 + (col - 1);
        float lo = even ? a : pb;
        float hi = even ? pa : b;
        atomic_pk_add_bf16(aggrow + nbase, lo, hi);
    }
}

// ---------------------------------------------------------------------------
// Weight prep: dst[b][c][r] = bf16(src[b][r][c])
// ---------------------------------------------------------------------------
__global__ void transpose_cvt(const float* __restrict__ src, short* __restrict__ dst,
                              int R, int C, int total) {
    int t = blockIdx.x * blockDim.x + threadIdx.x;
    if (t >= total) return;
    int rc = R * C;
    int b = t / rc;
    int rem = t - b * rc;
    int c = rem / R;
    int r = rem - c * R;
    dst[t] = f2bs(src[(size_t)b * rc + (size_t)r * C + c]);
}

// ---------------------------------------------------------------------------
// Edge prep: distances + per-atom histogram. 4 edges/thread for MLP.
// ---------------------------------------------------------------------------
__global__ void edge_prep4(const float* __restrict__ pos,
                           const int* __restrict__ idx_i,
                           const int* __restrict__ idx_j,
                           float* __restrict__ d_ij,
                           int* __restrict__ hist,
                           int E) {
    int b0 = blockIdx.x * 1024 + threadIdx.x;
    int ia[4], ib[4];
    bool val[4];
#pragma unroll
    for (int k = 0; k < 4; k++) {
        int e = b0 + k * 256;
        val[k] = (e < E);
        ia[k] = val[k] ? idx_i[e] : 0;
        ib[k] = val[k] ? idx_j[e] : 0;
    }
    float ax[4], ay[4], az[4], bx[4], by[4], bz[4];
#pragma unroll
    for (int k = 0; k < 4; k++) {
        const float* pa = pos + ia[k] * 3;
        ax[k] = pa[0]; ay[k] = pa[1]; az[k] = pa[2];
    }
#pragma unroll
    for (int k = 0; k < 4; k++) {
        const float* pb = pos + ib[k] * 3;
        bx[k] = pb[0]; by[k] = pb[1]; bz[k] = pb[2];
    }
#pragma unroll
    for (int k = 0; k < 4; k++) {
        if (!val[k]) continue;
        float dx = ax[k] - bx[k], dy = ay[k] - by[k], dz = az[k] - bz[k];
        float d = sqrtf(dx * dx + dy * dy + dz * dz);
        d_ij[b0 + k * 256] = d;
        if (d < CUTOFF_F) atomicAdd(&hist[ia[k]], 1);
    }
}

// ---------------------------------------------------------------------------
// Multi-block exclusive scan of hist[N] -> cursor[N]  (replaces the 160us
// single-block scan_hist). 3 stages; stage 2 runs on one tiny block.
// ---------------------------------------------------------------------------
__global__ __launch_bounds__(256) void scan_reduce(const int* __restrict__ hist,
                                                   int* __restrict__ partial, int N) {
    __shared__ int red[256];
    int b = blockIdx.x;
    int chunk = (N + SCB - 1) / SCB;
    int lo = b * chunk;
    int hi = min(lo + chunk, N);
    int s = 0;
    for (int i = lo + threadIdx.x; i < hi; i += 256) s += hist[i];
    red[threadIdx.x] = s;
    __syncthreads();
    for (int d = 128; d > 0; d >>= 1) {
        if (threadIdx.x < d) red[threadIdx.x] += red[threadIdx.x + d];
        __syncthreads();
    }
    if (threadIdx.x == 0) partial[b] = red[0];
}

__global__ __launch_bounds__(256) void scan_partials(int* __restrict__ partial) {
    __shared__ int sm[SCB];
    int t = threadIdx.x;
    sm[t] = partial[t];
    __syncthreads();
    for (int d = 1; d < SCB; d <<= 1) {
        int v = (t >= d) ? sm[t - d] : 0;
        __syncthreads();
        sm[t] += v;
        __syncthreads();
    }
    partial[t] = (t == 0) ? 0 : sm[t - 1];   // exclusive
}

__global__ __launch_bounds__(256) void scan_expand(const int* __restrict__ hist,
                                                   const int* __restrict__ partial,
                                                   int* __restrict__ cursor, int N) {
    __shared__ int tsum[256];
    int b = blockIdx.x;
    int chunk = (N + SCB - 1) / SCB;
    int lo = b * chunk;
    int hi = min(lo + chunk, N);
    int sub = (chunk + 255) / 256;
    int tlo = lo + threadIdx.x * sub;
    int thi = min(tlo + sub, hi);
    int s = 0;
    for (int i = tlo; i < thi; i++) s += hist[i];
    int t = threadIdx.x;
    tsum[t] = s;
    __syncthreads();
    for (int d = 1; d < 256; d <<= 1) {
        int v = (t >= d) ? tsum[t - d] : 0;
        __syncthreads();
        tsum[t] += v;
        __syncthreads();
    }
    int run = partial[b] + ((t == 0) ? 0 : tsum[t - 1]);
    for (int i = tlo; i < thi; i++) {
        cursor[i] = run;
        run += hist[i];
    }
}

// ---------------------------------------------------------------------------
// Scatter active edges into idx_i-grouped order. 4 edges/thread for MLP.
// Computes rcut for active edges only. After: cursor[a] == end of range.
// ---------------------------------------------------------------------------
__global__ void scatter_sorted4(const float* __restrict__ d_ij,
                                const int* __restrict__ idx_i,
                                const int* __restrict__ idx_j,
                                const int* __restrict__ edge_attr,
                                int* __restrict__ cursor,
                                float4* __restrict__ edata,
                                int* __restrict__ sIarr, int E) {
    int b0 = blockIdx.x * 1024 + threadIdx.x;
    float d[4]; int ii[4], jj[4], at[4]; bool act[4];
#pragma unroll
    for (int k = 0; k < 4; k++) {
        int e = b0 + k * 256;
        bool v = (e < E);
        d[k] = v ? d_ij[e] : 1e9f;
        act[k] = (d[k] < CUTOFF_F);
        ii[k] = act[k] ? idx_i[e] : 0;
        jj[k] = act[k] ? idx_j[e] : 0;
        at[k] = act[k] ? edge_attr[e] : 0;
    }
    int p[4];
#pragma unroll
    for (int k = 0; k < 4; k++)
        if (act[k]) p[k] = atomicAdd(&cursor[ii[k]], 1);
#pragma unroll
    for (int k = 0; k < 4; k++) {
        if (!act[k]) continue;
        float4 v;
        v.x = d[k];
        v.y = 0.5f * (__cosf(d[k] * PI_OVER_CUT) + 1.0f);
        v.z = __int_as_float(jj[k]);
        v.w = __int_as_float(at[k]);
        edata[p[k]] = v;
        sIarr[p[k]] = ii[k];
    }
}

// ---------------------------------------------------------------------------
// x = ele_emb[z] + res_emb[z_res]
// ---------------------------------------------------------------------------
__global__ void atom_embed(const int* __restrict__ z,
                           const int* __restrict__ z_res,
                           const float* __restrict__ ele_emb,
                           const float* __restrict__ res_emb,
                           float* __restrict__ x, int N) {
    int t = blockIdx.x * blockDim.x + threadIdx.x;
    if (t >= N * NB) return;
    int n = t >> 7, c = t & 127;
    x[t] = ele_emb[z[n] * NB + c] + res_emb[z_res[n] * NB + c];
}

// ---------------------------------------------------------------------------
// xf(bf16, permuted cols) = in(fp32) @ W  via MFMA. First-iteration in2f.
// ---------------------------------------------------------------------------
__global__ __launch_bounds__(256, 4) void node_in2f_mfma(
    const float* __restrict__ x, const short* __restrict__ WT,
    short* __restrict__ xf, int N) {
    __shared__ __align__(16) short XA[64 * HPAD];
    int a0 = blockIdx.x * 64;
    int t = threadIdx.x;
#pragma unroll
    for (int c = 0; c < 4; c++) {
        int chunk = t + c * 256;
        int row = chunk >> 4;
        int col = (chunk & 15) * 8;
        short v[8];
        if (a0 + row < N) {
            const float* src = x + (size_t)(a0 + row) * NB + col;
            float4 f0 = *(const float4*)src;
            float4 f1 = *(const float4*)(src + 4);
            v[0] = f2bs(f0.x); v[1] = f2bs(f0.y); v[2] = f2bs(f0.z); v[3] = f2bs(f0.w);
            v[4] = f2bs(f1.x); v[5] = f2bs(f1.y); v[6] = f2bs(f1.z); v[7] = f2bs(f1.w);
        } else {
#pragma unroll
            for (int j = 0; j < 8; j++) v[j] = 0;
        }
        *(bf16x8*)&XA[row * HPAD + col] = *(bf16x8*)v;
    }
    __syncthreads();

    int wid = t >> 6, lane = t & 63;
    int quad = lane >> 4, col = lane & 15;
    int mrow = wid * 16 + col;

    f32x4 acc[8] = {};
#pragma unroll
    for (int kt = 0; kt < 4; kt++) {
        bf16x8 a = *(bf16x8*)&XA[mrow * HPAD + kt * 32 + quad * 8];
#pragma unroll
        for (int nt = 0; nt < 8; nt++) {
            bf16x8 b = *(const bf16x8*)&WT[(nt * 16 + col) * NB + kt * 32 + quad * 8];
            acc[nt] = __builtin_amdgcn_mfma_f32_16x16x32_bf16(a, b, acc[nt], 0, 0, 0);
        }
    }
#pragma unroll
    for (int nt = 0; nt < 8; nt++) {
        int cst = col * 8 + nt;   // permuted storage col
#pragma unroll
        for (int r = 0; r < 4; r++) {
            int m = wid * 16 + quad * 4 + r;
            if (a0 + m < N) xf[(size_t)(a0 + m) * NB + cst] = f2bs(acc[nt][r]);
        }
    }
}

// ---------------------------------------------------------------------------
// Fused: v = ssp(agg@W1+b1)@W2+b2 ; x += v ; xf_next(bf16, permuted) = x @ Wn
// agg is bf16 in ORIGINAL feature order. After staging agg, this kernel
// re-zeroes its agg rows (replaces the inter-iteration memset).
// ---------------------------------------------------------------------------
__global__ __launch_bounds__(256, 4) void node_fused_mfma(
    short* __restrict__ agg,
    const short* __restrict__ W1T, const float* __restrict__ b1,
    const short* __restrict__ W2T, const float* __restrict__ b2,
    const short* __restrict__ WnT,
    float* __restrict__ x, short* __restrict__ xf, int N) {
    __shared__ __align__(16) short XA[64 * HPAD];
    __shared__ __align__(16) short H[64 * HPAD];
    int a0 = blockIdx.x * 64;
    int t = threadIdx.x;
#pragma unroll
    for (int c = 0; c < 4; c++) {
        int chunk = t + c * 256;
        int row = chunk >> 4;
        int col = (chunk & 15) * 8;
        bf16x8 v = {0, 0, 0, 0, 0, 0, 0, 0};
        if (a0 + row < N) {
            short* src = agg + (size_t)(a0 + row) * NB + col;
            v = *(const bf16x8*)src;
            *(bf16x8*)src = (bf16x8){0, 0, 0, 0, 0, 0, 0, 0};  // re-zero for next iter
        }
        *(bf16x8*)&XA[row * HPAD + col] = v;
    }
    __syncthreads();

    int wid = t >> 6, lane = t & 63;
    int quad = lane >> 4, col = lane & 15;
    int mrow = wid * 16 + col;

    // GEMM1 + ssp -> H
    {
        f32x4 acc[8] = {};
#pragma unroll
        for (int kt = 0; kt < 4; kt++) {
            bf16x8 a = *(bf16x8*)&XA[mrow * HPAD + kt * 32 + quad * 8];
#pragma unroll
            for (int nt = 0; nt < 8; nt++) {
                bf16x8 b = *(const bf16x8*)&W1T[(nt * 16 + col) * NB + kt * 32 + quad * 8];
                acc[nt] = __builtin_amdgcn_mfma_f32_16x16x32_bf16(a, b, acc[nt], 0, 0, 0);
            }
        }
#pragma unroll
        for (int nt = 0; nt < 8; nt++) {
            int n = nt * 16 + col;
            float bias = b1[n];
#pragma unroll
            for (int r = 0; r < 4; r++) {
                int m = wid * 16 + quad * 4 + r;
                H[m * HPAD + n] = f2bs(ssp_f(acc[nt][r] + bias));
            }
        }
    }
    __syncthreads();

    // GEMM2 + residual: x_new -> global fp32 + XA bf16 (reuse)
    {
        f32x4 acc[8] = {};
#pragma unroll
        for (int kt = 0; kt < 4; kt++) {
            bf16x8 a = *(bf16x8*)&H[mrow * HPAD + kt * 32 + quad * 8];
#pragma unroll
            for (int nt = 0; nt < 8; nt++) {
                bf16x8 b = *(const bf16x8*)&W2T[(nt * 16 + col) * NB + kt * 32 + quad * 8];
                acc[nt] = __builtin_amdgcn_mfma_f32_16x16x32_bf16(a, b, acc[nt], 0, 0, 0);
            }
        }
#pragma unroll
        for (int nt = 0; nt < 8; nt++) {
            int n = nt * 16 + col;
            float bias = b2[n];
#pragma unroll
            for (int r = 0; r < 4; r++) {
                int m = wid * 16 + quad * 4 + r;
                float xn = 0.0f;
                if (a0 + m < N) {
                    size_t o = (size_t)(a0 + m) * NB + n;
                    xn = x[o] + acc[nt][r] + bias;
                    x[o] = xn;
                }
                XA[m * HPAD + n] = f2bs(xn);
            }
        }
    }
    __syncthreads();

    // GEMM3: xf = x_new @ Wn  (bf16 out, permuted storage cols)
    {
        f32x4 acc[8] = {};
#pragma unroll
        for (int kt = 0; kt < 4; kt++) {
            bf16x8 a = *(bf16x8*)&XA[mrow * HPAD + kt * 32 + quad * 8];
#pragma unroll
            for (int nt = 0; nt < 8; nt++) {
                bf16x8 b = *(const bf16x8*)&WnT[(nt * 16 + col) * NB + kt * 32 + quad * 8];
                acc[nt] = __builtin_amdgcn_mfma_f32_16x16x32_bf16(a, b, acc[nt], 0, 0, 0);
            }
        }
#pragma unroll
        for (int nt = 0; nt < 8; nt++) {
            int cst = col * 8 + nt;
#pragma unroll
            for (int r = 0; r < 4; r++) {
                int m = wid * 16 + quad * 4 + r;
                if (a0 + m < N) xf[(size_t)(a0 + m) * NB + cst] = f2bs(acc[nt][r]);
            }
        }
    }
}

// ---------------------------------------------------------------------------
// Last iteration fused with head: v = ssp(agg@W1+b1)@W2+b2 ; xn = x + v ;
// h = silu(xn/||xn||) ; silu(h@hW1+hb1)@hW2 ; segment-sum by batch.
// ---------------------------------------------------------------------------
__global__ __launch_bounds__(256, 4) void node_out_head_mfma(
    const short* __restrict__ agg,
    const short* __restrict__ W1T, const float* __restrict__ b1,
    const short* __restrict__ W2T, const float* __restrict__ b2,
    const float* __restrict__ x, const int* __restrict__ batch,
    const short* __restrict__ hW1T, const float* __restrict__ hb1,
    const float* __restrict__ hW2,
    float* __restrict__ out, int N) {
    __shared__ __align__(16) short XA[64 * HPAD];
    __shared__ __align__(16) short H[64 * HPAD];
    __shared__ int sbat[64];
    __shared__ float rowval[64];
    int a0 = blockIdx.x * 64;
    int t = threadIdx.x;

    if (t < 64) sbat[t] = (a0 + t < N) ? batch[a0 + t] : -1;
#pragma unroll
    for (int c = 0; c < 4; c++) {
        int chunk = t + c * 256;
        int row = chunk >> 4;
        int col = (chunk & 15) * 8;
        bf16x8 v = {0, 0, 0, 0, 0, 0, 0, 0};
        if (a0 + row < N) v = *(const bf16x8*)&agg[(size_t)(a0 + row) * NB + col];
        *(bf16x8*)&XA[row * HPAD + col] = v;
    }
    __syncthreads();

    int wid = t >> 6, lane = t & 63;
    int quad = lane >> 4, col = lane & 15;
    int mrow = wid * 16 + col;

    // GEMM1 + ssp -> H
    {
        f32x4 acc[8] = {};
#pragma unroll
        for (int kt = 0; kt < 4; kt++) {
            bf16x8 a = *(bf16x8*)&XA[mrow * HPAD + kt * 32 + quad * 8];
#pragma unroll
            for (int nt = 0; nt < 8; nt++) {
                bf16x8 b = *(const bf16x8*)&W1T[(nt * 16 + col) * NB + kt * 32 + quad * 8];
                acc[nt] = __builtin_amdgcn_mfma_f32_16x16x32_bf16(a, b, acc[nt], 0, 0, 0);
            }
        }
#pragma unroll
        for (int nt = 0; nt < 8; nt++) {
            int n = nt * 16 + col;
            float bias = b1[n];
#pragma unroll
            for (int r = 0; r < 4; r++) {
                int m = wid * 16 + quad * 4 + r;
                H[m * HPAD + n] = f2bs(ssp_f(acc[nt][r] + bias));
            }
        }
    }
    __syncthreads();

    // GEMM2 + residual in registers; row sums of squares via 16-lane shuffle
    float xnv[8][4];
    float ssq[4] = {0.f, 0.f, 0.f, 0.f};
    {
        f32x4 acc[8] = {};
#pragma unroll
        for (int kt = 0; kt < 4; kt++) {
            bf16x8 a = *(bf16x8*)&H[mrow * HPAD + kt * 32 + quad * 8];
#pragma unroll
            for (int nt = 0; nt < 8; nt++) {
                bf16x8 b = *(const bf16x8*)&W2T[(nt * 16 + col) * NB + kt * 32 + quad * 8];
                acc[nt] = __builtin_amdgcn_mfma_f32_16x16x32_bf16(a, b, acc[nt], 0, 0, 0);
            }
        }
#pragma unroll
        for (int nt = 0; nt < 8; nt++) {
            int n = nt * 16 + col;
            float bias = b2[n];
#pragma unroll
            for (int r = 0; r < 4; r++) {
                int m = wid * 16 + quad * 4 + r;
                float xn = 0.0f;
                if (a0 + m < N) xn = x[(size_t)(a0 + m) * NB + n] + acc[nt][r] + bias;
                xnv[nt][r] = xn;
                ssq[r] += xn * xn;
            }
        }
    }
#pragma unroll
    for (int r = 0; r < 4; r++) {
#pragma unroll
        for (int m = 1; m < 16; m <<= 1) ssq[r] += __shfl_xor(ssq[r], m);
    }
    float inv[4];
#pragma unroll
    for (int r = 0; r < 4; r++) inv[r] = 1.0f / fmaxf(sqrtf(ssq[r]), 1e-12f);
    __syncthreads();
#pragma unroll
    for (int nt = 0; nt < 8; nt++) {
        int n = nt * 16 + col;
#pragma unroll
        for (int r = 0; r < 4; r++) {
            int m = wid * 16 + quad * 4 + r;
            XA[m * HPAD + n] = f2bs(silu_f(xnv[nt][r] * inv[r]));
        }
    }
    __syncthreads();

    // head GEMM: silu(h@hW1+hb1) dot hW2 per row
    f32x4 acc[8] = {};
#pragma unroll
    for (int kt = 0; kt < 4; kt++) {
        bf16x8 a = *(bf16x8*)&XA[mrow * HPAD + kt * 32 + quad * 8];
#pragma unroll
        for (int nt = 0; nt < 8; nt++) {
            bf16x8 b = *(const bf16x8*)&hW1T[(nt * 16 + col) * NB + kt * 32 + quad * 8];
            acc[nt] = __builtin_amdgcn_mfma_f32_16x16x32_bf16(a, b, acc[nt], 0, 0, 0);
        }
    }
    float partial[4] = {0.f, 0.f, 0.f, 0.f};
#pragma unroll
    for (int nt = 0; nt < 8; nt++) {
        int n = nt * 16 + col;
        float bias = hb1[n];
        float w2 = hW2[n];
#pragma unroll
        for (int r = 0; r < 4; r++) partial[r] += silu_f(acc[nt][r] + bias) * w2;
    }
#pragma unroll
    for (int r = 0; r < 4; r++) {
#pragma unroll
        for (int d = 1; d < 16; d <<= 1) partial[r] += __shfl_xor(partial[r], d);
    }
    if (col == 0) {
#pragma unroll
        for (int r = 0; r < 4; r++) rowval[wid * 16 + quad * 4 + r] = partial[r];
    }
    __syncthreads();

    if (t < 64) {
        int b = sbat[t];
        bool headf = (b >= 0) && (t == 0 || sbat[t - 1] != b);
        if (headf) {
            float s = 0.0f;
            int rr = t;
            while (rr < 64 && sbat[rr] == b) { s += rowval[rr]; rr++; }
            atomicAdd(&out[b], s);
        }
    }
}

// ---------------------------------------------------------------------------
// BARRIER-FREE fused edge kernel (r19, fastest measured). 4 independent
// waves/block, 16 edges each. Per-lane edge records + __shfl distribution;
// fA/H strictly wave-local; lgkmcnt(0)+sched_barrier(0) fences; post-stage
// gather hides under GEMM1+ssp+GEMM2; r15 merged pk-atomic epilogue.
// ---------------------------------------------------------------------------
__global__ __launch_bounds__(256, 4) void edge_fused_mfma(
    const float4* __restrict__ edata, const int* __restrict__ sIarr,
    const int* __restrict__ rowend, int natoms,
    const float* __restrict__ edge_emb,
    const short* __restrict__ W1T, const float* __restrict__ b1,
    const short* __restrict__ W2T, const float* __restrict__ b2,
    const short* __restrict__ xf, short* __restrict__ agg) {
    __shared__ __align__(16) short fA[64 * EPAD];
    __shared__ __align__(16) short H[64 * HPAD];

    int t = threadIdx.x;
    int wid = t >> 6, lane = t & 63;
    int quad = lane >> 4, col = lane & 15;
    int base = blockIdx.x * 64;
    int wbase = base + wid * 16;        // this wave's 16-edge window
    int el16 = lane & 15;               // lane holds edge record wbase+el16

    float4 ed = edata[wbase + el16];
    int sIv0 = sIarr[wbase + el16];
    int cnt = rowend[natoms - 1];
    if (base >= cnt) return;

    bool act = (wbase + el16) < cnt;
    float dv  = act ? ed.x : 1e9f;
    float rcv = act ? ed.y : 0.0f;
    int   jjv = act ? __float_as_int(ed.z) : 0;
    int   atv = act ? __float_as_int(ed.w) : 0;
    int   iiv = act ? sIv0 : 0;

    // stage A: f_ij tile (RBF + edge_emb), bf16 (wave-local rows)
    {
        int elA = lane >> 2;
        int r0 = (lane & 3) * 8;
        float d  = __shfl(dv, elA);
        int   at = __shfl(atv, elA);
        const float* em = edge_emb + at * NR + r0;
        short v[8];
#pragma unroll
        for (int j = 0; j < 8; j++) {
            float off = (float)(r0 + j) * RBF_STEP;
            float dd = d - off;
            v[j] = f2bs(__expf(RBF_COEFF * dd * dd) + em[j]);
        }
        *(bf16x8*)&fA[(wid * 16 + elA) * EPAD + r0] = *(bf16x8*)v;
    }

    // gather (permuted xf): one bf16x8 per edge = features {nt*16+col};
    // latency hides under GEMM1 + ssp + H staging + GEMM2.
    int e0l = quad * 4;                 // local index of this quad's 4 edges
    bf16x8 xv[4];
    const unsigned short* xg = (const unsigned short*)xf;
#pragma unroll
    for (int r = 0; r < 4; r++) {
        int jj = __shfl(jjv, e0l + r);
        xv[r] = *(const bf16x8*)&xg[(size_t)jj * NB + col * 8];
    }

    // wave-local LDS fence: fA writes -> GEMM1 reads
    asm volatile("s_waitcnt lgkmcnt(0)" ::: "memory");
    __builtin_amdgcn_sched_barrier(0);

    int mrow = wid * 16 + col;

    // GEMM1: hidden = f_ij @ W1 (K=32) ; ssp -> H (wave-local rows)
    {
        bf16x8 a1 = *(bf16x8*)&fA[mrow * EPAD + quad * 8];
        f32x4 acc[8];
#pragma unroll
        for (int nt = 0; nt < 8; nt++) {
            bf16x8 b = *(const bf16x8*)&W1T[(nt * 16 + col) * NR + quad * 8];
            acc[nt] = __builtin_amdgcn_mfma_f32_16x16x32_bf16(a1, b, (f32x4){0.f, 0.f, 0.f, 0.f}, 0, 0, 0);
        }
#pragma unroll
        for (int nt = 0; nt < 8; nt++) {
            int n = nt * 16 + col;
            float bias = b1[n];
#pragma unroll
            for (int r = 0; r < 4; r++) {
                int m = wid * 16 + quad * 4 + r;
                H[m * HPAD + n] = f2bs(ssp_f(acc[nt][r] + bias));
            }
        }
    }

    // wave-local LDS fence: H writes -> GEMM2 reads
    asm volatile("s_waitcnt lgkmcnt(0)" ::: "memory");
    __builtin_amdgcn_sched_barrier(0);

    // GEMM2: Wij = hidden @ W2 (K=128)
    f32x4 acc2[8] = {};
#pragma unroll
    for (int kt = 0; kt < 4; kt++) {
        bf16x8 a = *(bf16x8*)&H[mrow * HPAD + kt * 32 + quad * 8];
#pragma unroll
        for (int nt = 0; nt < 8; nt++) {
            bf16x8 b = *(const bf16x8*)&W2T[(nt * 16 + col) * NB + kt * 32 + quad * 8];
            acc2[nt] = __builtin_amdgcn_mfma_f32_16x16x32_bf16(a, b, acc2[nt], 0, 0, 0);
        }
    }

    // epilogue (r15): merge equal-atom runs over this thread's 4 edges,
    // flush each run with 4 packed-bf16 atomics (quad-uniform branches).
    float b2v[8];
#pragma unroll
    for (int nt = 0; nt < 8; nt++) b2v[nt] = b2[nt * 16 + col];

    int cur = __shfl(iiv, e0l);
    float accum[8] = {0.f, 0.f, 0.f, 0.f, 0.f, 0.f, 0.f, 0.f};
#pragma unroll
    for (int r = 0; r < 4; r++) {
        int ii = __shfl(iiv, e0l + r);
        float rc = __shfl(rcv, e0l + r);
        if (ii != cur) {
            flush_pk(agg + (size_t)cur * NB, accum, col);
#pragma unroll
            for (int nt = 0; nt < 8; nt++) accum[nt] = 0.f;
            cur = ii;
        }
#pragma unroll
        for (int nt = 0; nt < 8; nt++) {
            float w = (acc2[nt][r] + b2v[nt]) * rc;
            accum[nt] = fmaf(w, bs2f((unsigned short)xv[r][nt]), accum[nt]);
        }
    }
    flush_pk(agg + (size_t)cur * NB, accum, col);
}

// ---------------------------------------------------------------------------
extern "C" void kernel_launch(void* const* d_in, const int* in_sizes, int n_in,
                              void* d_out, int out_size, void* d_ws, size_t ws_size,
                              hipStream_t stream) {
    const int*   z        = (const int*)d_in[0];
    const int*   z_res    = (const int*)d_in[1];
    const float* pos      = (const float*)d_in[2];
    const int*   idx_i    = (const int*)d_in[3];
    const int*   idx_j    = (const int*)d_in[4];
    const int*   edge_attr= (const int*)d_in[5];
    const int*   batch    = (const int*)d_in[6];
    const float* ele_emb  = (const float*)d_in[7];
    const float* res_emb  = (const float*)d_in[8];
    const float* edge_emb = (const float*)d_in[9];
    const float* in2f_W   = (const float*)d_in[10];
    const float* filt_W1  = (const float*)d_in[11];
    const float* filt_b1  = (const float*)d_in[12];
    const float* filt_W2  = (const float*)d_in[13];
    const float* filt_b2  = (const float*)d_in[14];
    const float* f2out_W1 = (const float*)d_in[15];
    const float* f2out_b1 = (const float*)d_in[16];
    const float* f2out_W2 = (const float*)d_in[17];
    const float* f2out_b2 = (const float*)d_in[18];
    const float* head_W1  = (const float*)d_in[19];
    const float* head_b1  = (const float*)d_in[20];
    const float* head_W2  = (const float*)d_in[21];

    const int N = in_sizes[0];
    const int E = in_sizes[3];

    char* p = (char*)d_ws;
    size_t off = 0;
    auto carve = [&](size_t bytes) -> void* {
        void* q = p + off;
        off = (off + bytes + 255) & ~(size_t)255;
        return q;
    };
    float*  d_d      = (float*)carve((size_t)E * 4);
    float4* edata    = (float4*)carve((size_t)E * 16);
    int*    sIarr    = (int*)carve((size_t)E * 4);
    int*    hist     = (int*)carve((size_t)N * 4);
    int*    cursor   = (int*)carve((size_t)N * 4);
    int*    partial  = (int*)carve((size_t)SCB * 4);
    float*  x_buf    = (float*)carve((size_t)N * NB * 4);
    short*  xf_buf   = (short*)carve((size_t)N * NB * 2);
    short*  agg      = (short*)carve((size_t)N * NB * 2);
    short*  in2f_WT  = (short*)carve((size_t)6 * NB * NB * 2);
    short*  fW1T     = (short*)carve((size_t)6 * NR * NB * 2);
    short*  fW2T     = (short*)carve((size_t)6 * NB * NB * 2);
    short*  oW1T     = (short*)carve((size_t)6 * NB * NB * 2);
    short*  oW2T     = (short*)carve((size_t)6 * NB * NB * 2);
    short*  hW1T     = (short*)carve((size_t)NB * NB * 2);
    (void)ws_size;

    // weight prep (bf16 transposed)
    {
        int tot = 6 * NB * NB;
        transpose_cvt<<<(tot + 255) / 256, 256, 0, stream>>>(in2f_W, in2f_WT, NB, NB, tot);
        transpose_cvt<<<(tot + 255) / 256, 256, 0, stream>>>(filt_W2, fW2T, NB, NB, tot);
        transpose_cvt<<<(tot + 255) / 256, 256, 0, stream>>>(f2out_W1, oW1T, NB, NB, tot);
        transpose_cvt<<<(tot + 255) / 256, 256, 0, stream>>>(f2out_W2, oW2T, NB, NB, tot);
        int tot1 = 6 * NR * NB;
        transpose_cvt<<<(tot1 + 255) / 256, 256, 0, stream>>>(filt_W1, fW1T, NR, NB, tot1);
        int tot2 = NB * NB;
        transpose_cvt<<<(tot2 + 255) / 256, 256, 0, stream>>>(head_W1, hW1T, NB, NB, tot2);
    }

    // edge prep + idx_i-grouped sort with packed records
    hipMemsetAsync(hist, 0, (size_t)N * 4, stream);
    int nblk_e4 = (E + 1023) / 1024;
    edge_prep4<<<nblk_e4, 256, 0, stream>>>(pos, idx_i, idx_j, d_d, hist, E);
    // multi-block exclusive scan: hist -> cursor (replaces 160us scan_hist)
    scan_reduce<<<SCB, 256, 0, stream>>>(hist, partial, N);
    scan_partials<<<1, SCB, 0, stream>>>(partial);
    scan_expand<<<SCB, 256, 0, stream>>>(hist, partial, cursor, N);
    scatter_sorted4<<<nblk_e4, 256, 0, stream>>>(d_d, idx_i, idx_j, edge_attr,
                                                 cursor, edata, sIarr, E);
    // cursor[a] is now the END of atom a's sorted range; cursor[N-1] = count.

    atom_embed<<<(N * NB + 255) / 256, 256, 0, stream>>>(z, z_res, ele_emb, res_emb, x_buf, N);

    int nblk_atom64 = (N + 63) / 64;
    int nblk_edge = (E + 63) / 64;

    node_in2f_mfma<<<nblk_atom64, 256, 0, stream>>>(x_buf, in2f_WT, xf_buf, N);
    hipMemsetAsync(d_out, 0, (size_t)out_size * sizeof(float), stream);
    hipMemsetAsync(agg, 0, (size_t)N * NB * 2, stream);   // once; node_fused re-zeroes
    for (int i = 0; i < 6; i++) {
        edge_fused_mfma<<<nblk_edge, 256, 0, stream>>>(
            edata, sIarr, cursor, N, edge_emb,
            fW1T + (size_t)i * NR * NB, filt_b1 + (size_t)i * NB,
            fW2T + (size_t)i * NB * NB, filt_b2 + (size_t)i * NB,
            xf_buf, agg);
        if (i < 5) {
            node_fused_mfma<<<nblk_atom64, 256, 0, stream>>>(
                agg, oW1T + (size_t)i * NB * NB, f2out_b1 + (size_t)i * NB,
                oW2T + (size_t)i * NB * NB, f2out_b2 + (size_t)i * NB,
                in2f_WT + (size_t)(i + 1) * NB * NB,
                x_buf, xf_buf, N);
        } else {
            node_out_head_mfma<<<nblk_atom64, 256, 0, stream>>>(
                agg, oW1T + (size_t)i * NB * NB, f2out_b1 + (size_t)i * NB,
                oW2T + (size_t)i * NB * NB, f2out_b2 + (size_t)i * NB,
                x_buf, batch, hW1T, head_b1, head_W2,
                (float*)d_out, N);
        }
    }
}

// Round 9
// 1923.491 us; speedup vs baseline: 1.6018x; 1.1477x over previous
//
#include <hip/hip_runtime.h>
#include <hip/hip_bf16.h>
#include <math.h>

#define NB 128
#define NR 32
#define EPAD 40    // fA row stride in shorts
#define HPAD 136   // H/XA row stride in shorts (272B, 16B-aligned rows)
#define SCB 256    // scan blocks

// r24 == r23 resubmit (container infra failure, no data; non-ASCII comment
// char scrubbed). 2-SUBTILE REGISTER-REUSE edge wave. Ledger exonerates
// atomics (r18), occupancy (r17), barriers (r19), block tile (r17).
// Constant through all: each wave fetches ALL of W2T(32KB)+W1T(8KB) for
// only 16 edges of output (~1.7GB weight reads/dispatch). r24: 128
// edges/block, each wave owns 32 edges as two M=16 subtiles; weight
// B-fragments loaded ONCE per wave into registers, consumed by both
// subtiles -> weight traffic halved, wave count halved. LDS 44KB -> 3
// blk/CU (~12 waves/CU, same as today). Gather placement + pk-atomic
// epilogue unchanged (isolates the weight variable). r22 fast-scan
// retained (-150us, verified).
// Falsified: r5 LDS gather staging, r6 owner-computes fusion, r7 permuted
// scatter, r10 pre-barrier gather, r12 analytic A-fragment, r14 2-tile
// pipeline, r16 LDS fp32 agg, r17 bigger block (same per-wave M), r18
// cross-quad merge, r20/r21 dispatch split.

static constexpr float CUTOFF_F    = 10.0f;
static constexpr float RBF_STEP    = 10.0f / 31.0f;
static constexpr float RBF_COEFF   = -4.805f;           // -0.5/(10/31)^2
static constexpr float LOG2_F      = 0.69314718055994531f;
static constexpr float PI_OVER_CUT = 0.314159265358979f;

typedef __attribute__((ext_vector_type(8))) short bf16x8;
typedef __attribute__((ext_vector_type(2))) short bf16x2;
typedef __attribute__((ext_vector_type(4))) float f32x4;

__device__ __forceinline__ short f2bs(float x) {
    __hip_bfloat16 h = __float2bfloat16(x);   // RNE
    return *reinterpret_cast<short*>(&h);
}
__device__ __forceinline__ float bs2f(unsigned short u) {
    unsigned int v = ((unsigned int)u) << 16;
    return __uint_as_float(v);
}
__device__ __forceinline__ float ssp_f(float v) {
    return fmaxf(v, 0.0f) + __logf(1.0f + __expf(-fabsf(v))) - LOG2_F;
}
__device__ __forceinline__ float silu_f(float v) {
    return v / (1.0f + __expf(-v));
}

// packed bf16 atomic add (2 features per op)
__device__ __forceinline__ void atomic_pk_add_bf16(short* addr, float lo, float hi) {
#if __has_builtin(__builtin_amdgcn_global_atomic_fadd_v2bf16)
    typedef bf16x2 __attribute__((address_space(1))) *gptr;
    bf16x2 v;
    v[0] = f2bs(lo);
    v[1] = f2bs(hi);
    __builtin_amdgcn_global_atomic_fadd_v2bf16((gptr)(unsigned long long)addr, v);
#else
    unsigned int* w = (unsigned int*)addr;
    unsigned int old = *w, assumed;
    do {
        assumed = old;
        float fl = bs2f((unsigned short)(assumed & 0xffff)) + lo;
        float fh = bs2f((unsigned short)(assumed >> 16)) + hi;
        unsigned int nv = ((unsigned int)(unsigned short)f2bs(fh) << 16) |
                          (unsigned short)f2bs(fl);
        old = atomicCAS(w, assumed, nv);
    } while (old != assumed);
#endif
}

// flush one merged run: 8 accumulated features/lane -> 4 pk atomics/lane.
// Run boundaries are quad-uniform so the lane^1 shuffles pair active lanes.
__device__ __forceinline__ void flush_pk(short* aggrow, const float* accum, int col) {
    bool even = ((col & 1) == 0);
#pragma unroll
    for (int q = 0; q < 4; q++) {
        float a = accum[2 * q], b = accum[2 * q + 1];
        float pa = __shfl_xor(a, 1);   // feature (2q)*16 + (col^1)
        float pb = __shfl_xor(b, 1);
        int nbase = even ? (2 * q) * 16 + col : (2 * q + 1) * 16 + (col - 1);
        float lo = even ? a : pb;
        float hi = even ? pa : b;
        atomic_pk_add_bf16(aggrow + nbase, lo, hi);
    }
}

// ---------------------------------------------------------------------------
// Weight prep: dst[b][c][r] = bf16(src[b][r][c])
// ---------------------------------------------------------------------------
__global__ void transpose_cvt(const float* __restrict__ src, short* __restrict__ dst,
                              int R, int C, int total) {
    int t = blockIdx.x * blockDim.x + threadIdx.x;
    if (t >= total) return;
    int rc = R * C;
    int b = t / rc;
    int rem = t - b * rc;
    int c = rem / R;
    int r = rem - c * R;
    dst[t] = f2bs(src[(size_t)b * rc + (size_t)r * C + c]);
}

// ---------------------------------------------------------------------------
// Edge prep: distances + per-atom histogram. 4 edges/thread for MLP.
// ---------------------------------------------------------------------------
__global__ void edge_prep4(const float* __restrict__ pos,
                           const int* __restrict__ idx_i,
                           const int* __restrict__ idx_j,
                           float* __restrict__ d_ij,
                           int* __restrict__ hist,
                           int E) {
    int b0 = blockIdx.x * 1024 + threadIdx.x;
    int ia[4], ib[4];
    bool val[4];
#pragma unroll
    for (int k = 0; k < 4; k++) {
        int e = b0 + k * 256;
        val[k] = (e < E);
        ia[k] = val[k] ? idx_i[e] : 0;
        ib[k] = val[k] ? idx_j[e] : 0;
    }
    float ax[4], ay[4], az[4], bx[4], by[4], bz[4];
#pragma unroll
    for (int k = 0; k < 4; k++) {
        const float* pa = pos + ia[k] * 3;
        ax[k] = pa[0]; ay[k] = pa[1]; az[k] = pa[2];
    }
#pragma unroll
    for (int k = 0; k < 4; k++) {
        const float* pb = pos + ib[k] * 3;
        bx[k] = pb[0]; by[k] = pb[1]; bz[k] = pb[2];
    }
#pragma unroll
    for (int k = 0; k < 4; k++) {
        if (!val[k]) continue;
        float dx = ax[k] - bx[k], dy = ay[k] - by[k], dz = az[k] - bz[k];
        float d = sqrtf(dx * dx + dy * dy + dz * dz);
        d_ij[b0 + k * 256] = d;
        if (d < CUTOFF_F) atomicAdd(&hist[ia[k]], 1);
    }
}

// ---------------------------------------------------------------------------
// Multi-block exclusive scan of hist[N] -> cursor[N]  (r22, ~12us).
// ---------------------------------------------------------------------------
__global__ __launch_bounds__(256) void scan_reduce(const int* __restrict__ hist,
                                                   int* __restrict__ partial, int N) {
    __shared__ int red[256];
    int b = blockIdx.x;
    int chunk = (N + SCB - 1) / SCB;
    int lo = b * chunk;
    int hi = min(lo + chunk, N);
    int s = 0;
    for (int i = lo + threadIdx.x; i < hi; i += 256) s += hist[i];
    red[threadIdx.x] = s;
    __syncthreads();
    for (int d = 128; d > 0; d >>= 1) {
        if (threadIdx.x < d) red[threadIdx.x] += red[threadIdx.x + d];
        __syncthreads();
    }
    if (threadIdx.x == 0) partial[b] = red[0];
}

__global__ __launch_bounds__(256) void scan_partials(int* __restrict__ partial) {
    __shared__ int sm[SCB];
    int t = threadIdx.x;
    sm[t] = partial[t];
    __syncthreads();
    for (int d = 1; d < SCB; d <<= 1) {
        int v = (t >= d) ? sm[t - d] : 0;
        __syncthreads();
        sm[t] += v;
        __syncthreads();
    }
    partial[t] = (t == 0) ? 0 : sm[t - 1];   // exclusive
}

__global__ __launch_bounds__(256) void scan_expand(const int* __restrict__ hist,
                                                   const int* __restrict__ partial,
                                                   int* __restrict__ cursor, int N) {
    __shared__ int tsum[256];
    int b = blockIdx.x;
    int chunk = (N + SCB - 1) / SCB;
    int lo = b * chunk;
    int hi = min(lo + chunk, N);
    int sub = (chunk + 255) / 256;
    int tlo = lo + threadIdx.x * sub;
    int thi = min(tlo + sub, hi);
    int s = 0;
    for (int i = tlo; i < thi; i++) s += hist[i];
    int t = threadIdx.x;
    tsum[t] = s;
    __syncthreads();
    for (int d = 1; d < 256; d <<= 1) {
        int v = (t >= d) ? tsum[t - d] : 0;
        __syncthreads();
        tsum[t] += v;
        __syncthreads();
    }
    int run = partial[b] + ((t == 0) ? 0 : tsum[t - 1]);
    for (int i = tlo; i < thi; i++) {
        cursor[i] = run;
        run += hist[i];
    }
}

// ---------------------------------------------------------------------------
// Scatter active edges into idx_i-grouped order. 4 edges/thread for MLP.
// Computes rcut for active edges only. After: cursor[a] == end of range.
// ---------------------------------------------------------------------------
__global__ void scatter_sorted4(const float* __restrict__ d_ij,
                                const int* __restrict__ idx_i,
                                const int* __restrict__ idx_j,
                                const int* __restrict__ edge_attr,
                                int* __restrict__ cursor,
                                float4* __restrict__ edata,
                                int* __restrict__ sIarr, int E) {
    int b0 = blockIdx.x * 1024 + threadIdx.x;
    float d[4]; int ii[4], jj[4], at[4]; bool act[4];
#pragma unroll
    for (int k = 0; k < 4; k++) {
        int e = b0 + k * 256;
        bool v = (e < E);
        d[k] = v ? d_ij[e] : 1e9f;
        act[k] = (d[k] < CUTOFF_F);
        ii[k] = act[k] ? idx_i[e] : 0;
        jj[k] = act[k] ? idx_j[e] : 0;
        at[k] = act[k] ? edge_attr[e] : 0;
    }
    int p[4];
#pragma unroll
    for (int k = 0; k < 4; k++)
        if (act[k]) p[k] = atomicAdd(&cursor[ii[k]], 1);
#pragma unroll
    for (int k = 0; k < 4; k++) {
        if (!act[k]) continue;
        float4 v;
        v.x = d[k];
        v.y = 0.5f * (__cosf(d[k] * PI_OVER_CUT) + 1.0f);
        v.z = __int_as_float(jj[k]);
        v.w = __int_as_float(at[k]);
        edata[p[k]] = v;
        sIarr[p[k]] = ii[k];
    }
}

// ---------------------------------------------------------------------------
// x = ele_emb[z] + res_emb[z_res]
// ---------------------------------------------------------------------------
__global__ void atom_embed(const int* __restrict__ z,
                           const int* __restrict__ z_res,
                           const float* __restrict__ ele_emb,
                           const float* __restrict__ res_emb,
                           float* __restrict__ x, int N) {
    int t = blockIdx.x * blockDim.x + threadIdx.x;
    if (t >= N * NB) return;
    int n = t >> 7, c = t & 127;
    x[t] = ele_emb[z[n] * NB + c] + res_emb[z_res[n] * NB + c];
}

// ---------------------------------------------------------------------------
// xf(bf16, permuted cols) = in(fp32) @ W  via MFMA. First-iteration in2f.
// ---------------------------------------------------------------------------
__global__ __launch_bounds__(256, 4) void node_in2f_mfma(
    const float* __restrict__ x, const short* __restrict__ WT,
    short* __restrict__ xf, int N) {
    __shared__ __align__(16) short XA[64 * HPAD];
    int a0 = blockIdx.x * 64;
    int t = threadIdx.x;
#pragma unroll
    for (int c = 0; c < 4; c++) {
        int chunk = t + c * 256;
        int row = chunk >> 4;
        int col = (chunk & 15) * 8;
        short v[8];
        if (a0 + row < N) {
            const float* src = x + (size_t)(a0 + row) * NB + col;
            float4 f0 = *(const float4*)src;
            float4 f1 = *(const float4*)(src + 4);
            v[0] = f2bs(f0.x); v[1] = f2bs(f0.y); v[2] = f2bs(f0.z); v[3] = f2bs(f0.w);
            v[4] = f2bs(f1.x); v[5] = f2bs(f1.y); v[6] = f2bs(f1.z); v[7] = f2bs(f1.w);
        } else {
#pragma unroll
            for (int j = 0; j < 8; j++) v[j] = 0;
        }
        *(bf16x8*)&XA[row * HPAD + col] = *(bf16x8*)v;
    }
    __syncthreads();

    int wid = t >> 6, lane = t & 63;
    int quad = lane >> 4, col = lane & 15;
    int mrow = wid * 16 + col;

    f32x4 acc[8] = {};
#pragma unroll
    for (int kt = 0; kt < 4; kt++) {
        bf16x8 a = *(bf16x8*)&XA[mrow * HPAD + kt * 32 + quad * 8];
#pragma unroll
        for (int nt = 0; nt < 8; nt++) {
            bf16x8 b = *(const bf16x8*)&WT[(nt * 16 + col) * NB + kt * 32 + quad * 8];
            acc[nt] = __builtin_amdgcn_mfma_f32_16x16x32_bf16(a, b, acc[nt], 0, 0, 0);
        }
    }
#pragma unroll
    for (int nt = 0; nt < 8; nt++) {
        int cst = col * 8 + nt;   // permuted storage col
#pragma unroll
        for (int r = 0; r < 4; r++) {
            int m = wid * 16 + quad * 4 + r;
            if (a0 + m < N) xf[(size_t)(a0 + m) * NB + cst] = f2bs(acc[nt][r]);
        }
    }
}

// ---------------------------------------------------------------------------
// Fused: v = ssp(agg@W1+b1)@W2+b2 ; x += v ; xf_next(bf16, permuted) = x @ Wn
// agg is bf16 in ORIGINAL feature order. After staging agg, this kernel
// re-zeroes its agg rows (replaces the inter-iteration memset).
// ---------------------------------------------------------------------------
__global__ __launch_bounds__(256, 4) void node_fused_mfma(
    short* __restrict__ agg,
    const short* __restrict__ W1T, const float* __restrict__ b1,
    const short* __restrict__ W2T, const float* __restrict__ b2,
    const short* __restrict__ WnT,
    float* __restrict__ x, short* __restrict__ xf, int N) {
    __shared__ __align__(16) short XA[64 * HPAD];
    __shared__ __align__(16) short H[64 * HPAD];
    int a0 = blockIdx.x * 64;
    int t = threadIdx.x;
#pragma unroll
    for (int c = 0; c < 4; c++) {
        int chunk = t + c * 256;
        int row = chunk >> 4;
        int col = (chunk & 15) * 8;
        bf16x8 v = {0, 0, 0, 0, 0, 0, 0, 0};
        if (a0 + row < N) {
            short* src = agg + (size_t)(a0 + row) * NB + col;
            v = *(const bf16x8*)src;
            *(bf16x8*)src = (bf16x8){0, 0, 0, 0, 0, 0, 0, 0};  // re-zero for next iter
        }
        *(bf16x8*)&XA[row * HPAD + col] = v;
    }
    __syncthreads();

    int wid = t >> 6, lane = t & 63;
    int quad = lane >> 4, col = lane & 15;
    int mrow = wid * 16 + col;

    // GEMM1 + ssp -> H
    {
        f32x4 acc[8] = {};
#pragma unroll
        for (int kt = 0; kt < 4; kt++) {
            bf16x8 a = *(bf16x8*)&XA[mrow * HPAD + kt * 32 + quad * 8];
#pragma unroll
            for (int nt = 0; nt < 8; nt++) {
                bf16x8 b = *(const bf16x8*)&W1T[(nt * 16 + col) * NB + kt * 32 + quad * 8];
                acc[nt] = __builtin_amdgcn_mfma_f32_16x16x32_bf16(a, b, acc[nt], 0, 0, 0);
            }
        }
#pragma unroll
        for (int nt = 0; nt < 8; nt++) {
            int n = nt * 16 + col;
            float bias = b1[n];
#pragma unroll
            for (int r = 0; r < 4; r++) {
                int m = wid * 16 + quad * 4 + r;
                H[m * HPAD + n] = f2bs(ssp_f(acc[nt][r] + bias));
            }
        }
    }
    __syncthreads();

    // GEMM2 + residual: x_new -> global fp32 + XA bf16 (reuse)
    {
        f32x4 acc[8] = {};
#pragma unroll
        for (int kt = 0; kt < 4; kt++) {
            bf16x8 a = *(bf16x8*)&H[mrow * HPAD + kt * 32 + quad * 8];
#pragma unroll
            for (int nt = 0; nt < 8; nt++) {
                bf16x8 b = *(const bf16x8*)&W2T[(nt * 16 + col) * NB + kt * 32 + quad * 8];
                acc[nt] = __builtin_amdgcn_mfma_f32_16x16x32_bf16(a, b, acc[nt], 0, 0, 0);
            }
        }
#pragma unroll
        for (int nt = 0; nt < 8; nt++) {
            int n = nt * 16 + col;
            float bias = b2[n];
#pragma unroll
            for (int r = 0; r < 4; r++) {
                int m = wid * 16 + quad * 4 + r;
                float xn = 0.0f;
                if (a0 + m < N) {
                    size_t o = (size_t)(a0 + m) * NB + n;
                    xn = x[o] + acc[nt][r] + bias;
                    x[o] = xn;
                }
                XA[m * HPAD + n] = f2bs(xn);
            }
        }
    }
    __syncthreads();

    // GEMM3: xf = x_new @ Wn  (bf16 out, permuted storage cols)
    {
        f32x4 acc[8] = {};
#pragma unroll
        for (int kt = 0; kt < 4; kt++) {
            bf16x8 a = *(bf16x8*)&XA[mrow * HPAD + kt * 32 + quad * 8];
#pragma unroll
            for (int nt = 0; nt < 8; nt++) {
                bf16x8 b = *(const bf16x8*)&WnT[(nt * 16 + col) * NB + kt * 32 + quad * 8];
                acc[nt] = __builtin_amdgcn_mfma_f32_16x16x32_bf16(a, b, acc[nt], 0, 0, 0);
            }
        }
#pragma unroll
        for (int nt = 0; nt < 8; nt++) {
            int cst = col * 8 + nt;
#pragma unroll
            for (int r = 0; r < 4; r++) {
                int m = wid * 16 + quad * 4 + r;
                if (a0 + m < N) xf[(size_t)(a0 + m) * NB + cst] = f2bs(acc[nt][r]);
            }
        }
    }
}

// ---------------------------------------------------------------------------
// Last iteration fused with head: v = ssp(agg@W1+b1)@W2+b2 ; xn = x + v ;
// h = silu(xn/||xn||) ; silu(h@hW1+hb1)@hW2 ; segment-sum by batch.
// ---------------------------------------------------------------------------
__global__ __launch_bounds__(256, 4) void node_out_head_mfma(
    const short* __restrict__ agg,
    const short* __restrict__ W1T, const float* __restrict__ b1,
    const short* __restrict__ W2T, const float* __restrict__ b2,
    const float* __restrict__ x, const int* __restrict__ batch,
    const short* __restrict__ hW1T, const float* __restrict__ hb1,
    const float* __restrict__ hW2,
    float* __restrict__ out, int N) {
    __shared__ __align__(16) short XA[64 * HPAD];
    __shared__ __align__(16) short H[64 * HPAD];
    __shared__ int sbat[64];
    __shared__ float rowval[64];
    int a0 = blockIdx.x * 64;
    int t = threadIdx.x;

    if (t < 64) sbat[t] = (a0 + t < N) ? batch[a0 + t] : -1;
#pragma unroll
    for (int c = 0; c < 4; c++) {
        int chunk = t + c * 256;
        int row = chunk >> 4;
        int col = (chunk & 15) * 8;
        bf16x8 v = {0, 0, 0, 0, 0, 0, 0, 0};
        if (a0 + row < N) v = *(const bf16x8*)&agg[(size_t)(a0 + row) * NB + col];
        *(bf16x8*)&XA[row * HPAD + col] = v;
    }
    __syncthreads();

    int wid = t >> 6, lane = t & 63;
    int quad = lane >> 4, col = lane & 15;
    int mrow = wid * 16 + col;

    // GEMM1 + ssp -> H
    {
        f32x4 acc[8] = {};
#pragma unroll
        for (int kt = 0; kt < 4; kt++) {
            bf16x8 a = *(bf16x8*)&XA[mrow * HPAD + kt * 32 + quad * 8];
#pragma unroll
            for (int nt = 0; nt < 8; nt++) {
                bf16x8 b = *(const bf16x8*)&W1T[(nt * 16 + col) * NB + kt * 32 + quad * 8];
                acc[nt] = __builtin_amdgcn_mfma_f32_16x16x32_bf16(a, b, acc[nt], 0, 0, 0);
            }
        }
#pragma unroll
        for (int nt = 0; nt < 8; nt++) {
            int n = nt * 16 + col;
            float bias = b1[n];
#pragma unroll
            for (int r = 0; r < 4; r++) {
                int m = wid * 16 + quad * 4 + r;
                H[m * HPAD + n] = f2bs(ssp_f(acc[nt][r] + bias));
            }
        }
    }
    __syncthreads();

    // GEMM2 + residual in registers; row sums of squares via 16-lane shuffle
    float xnv[8][4];
    float ssq[4] = {0.f, 0.f, 0.f, 0.f};
    {
        f32x4 acc[8] = {};
#pragma unroll
        for (int kt = 0; kt < 4; kt++) {
            bf16x8 a = *(bf16x8*)&H[mrow * HPAD + kt * 32 + quad * 8];
#pragma unroll
            for (int nt = 0; nt < 8; nt++) {
                bf16x8 b = *(const bf16x8*)&W2T[(nt * 16 + col) * NB + kt * 32 + quad * 8];
                acc[nt] = __builtin_amdgcn_mfma_f32_16x16x32_bf16(a, b, acc[nt], 0, 0, 0);
            }
        }
#pragma unroll
        for (int nt = 0; nt < 8; nt++) {
            int n = nt * 16 + col;
            float bias = b2[n];
#pragma unroll
            for (int r = 0; r < 4; r++) {
                int m = wid * 16 + quad * 4 + r;
                float xn = 0.0f;
                if (a0 + m < N) xn = x[(size_t)(a0 + m) * NB + n] + acc[nt][r] + bias;
                xnv[nt][r] = xn;
                ssq[r] += xn * xn;
            }
        }
    }
#pragma unroll
    for (int r = 0; r < 4; r++) {
#pragma unroll
        for (int m = 1; m < 16; m <<= 1) ssq[r] += __shfl_xor(ssq[r], m);
    }
    float inv[4];
#pragma unroll
    for (int r = 0; r < 4; r++) inv[r] = 1.0f / fmaxf(sqrtf(ssq[r]), 1e-12f);
    __syncthreads();
#pragma unroll
    for (int nt = 0; nt < 8; nt++) {
        int n = nt * 16 + col;
#pragma unroll
        for (int r = 0; r < 4; r++) {
            int m = wid * 16 + quad * 4 + r;
            XA[m * HPAD + n] = f2bs(silu_f(xnv[nt][r] * inv[r]));
        }
    }
    __syncthreads();

    // head GEMM: silu(h@hW1+hb1) dot hW2 per row
    f32x4 acc[8] = {};
#pragma unroll
    for (int kt = 0; kt < 4; kt++) {
        bf16x8 a = *(bf16x8*)&XA[mrow * HPAD + kt * 32 + quad * 8];
#pragma unroll
        for (int nt = 0; nt < 8; nt++) {
            bf16x8 b = *(const bf16x8*)&hW1T[(nt * 16 + col) * NB + kt * 32 + quad * 8];
            acc[nt] = __builtin_amdgcn_mfma_f32_16x16x32_bf16(a, b, acc[nt], 0, 0, 0);
        }
    }
    float partial[4] = {0.f, 0.f, 0.f, 0.f};
#pragma unroll
    for (int nt = 0; nt < 8; nt++) {
        int n = nt * 16 + col;
        float bias = hb1[n];
        float w2 = hW2[n];
#pragma unroll
        for (int r = 0; r < 4; r++) partial[r] += silu_f(acc[nt][r] + bias) * w2;
    }
#pragma unroll
    for (int r = 0; r < 4; r++) {
#pragma unroll
        for (int d = 1; d < 16; d <<= 1) partial[r] += __shfl_xor(partial[r], d);
    }
    if (col == 0) {
#pragma unroll
        for (int r = 0; r < 4; r++) rowval[wid * 16 + quad * 4 + r] = partial[r];
    }
    __syncthreads();

    if (t < 64) {
        int b = sbat[t];
        bool headf = (b >= 0) && (t == 0 || sbat[t - 1] != b);
        if (headf) {
            float s = 0.0f;
            int rr = t;
            while (rr < 64 && sbat[rr] == b) { s += rowval[rr]; rr++; }
            atomicAdd(&out[b], s);
        }
    }
}

// ---------------------------------------------------------------------------
// BARRIER-FREE 2-subtile edge kernel (r24). 128 edges/block, 4 waves, each
// wave owns 32 contiguous edges as two M=16 subtiles. Weight B-fragments
// (W1T, W2T) loaded once per wave into registers and reused by both
// subtiles -> weight traffic halved. fA/H wave-local; lgkmcnt fences;
// r15 merged pk-atomic epilogue per subtile.
// ---------------------------------------------------------------------------
__global__ __launch_bounds__(256, 3) void edge_fused_mfma(
    const float4* __restrict__ edata, const int* __restrict__ sIarr,
    const int* __restrict__ rowend, int natoms,
    const float* __restrict__ edge_emb,
    const short* __restrict__ W1T, const float* __restrict__ b1,
    const short* __restrict__ W2T, const float* __restrict__ b2,
    const short* __restrict__ xf, short* __restrict__ agg) {
    __shared__ __align__(16) short fA[128 * EPAD];
    __shared__ __align__(16) short H[128 * HPAD];

    int t = threadIdx.x;
    int wid = t >> 6, lane = t & 63;
    int quad = lane >> 4, col = lane & 15;
    int base = blockIdx.x * 128;
    int wbase = base + wid * 32;        // this wave's 32-edge window
    int el32 = lane & 31;               // lane holds record of edge wbase+el32

    // issue record loads immediately (edata/sIarr are E-sized)
    float4 ed = edata[wbase + el32];
    int sIv0 = sIarr[wbase + el32];
    int cnt = rowend[natoms - 1];
    if (base >= cnt) return;

    bool act = (wbase + el32) < cnt;
    float dv  = act ? ed.x : 1e9f;
    float rcv = act ? ed.y : 0.0f;
    int   jjv = act ? __float_as_int(ed.z) : 0;
    int   atv = act ? __float_as_int(ed.w) : 0;
    int   iiv = act ? sIv0 : 0;

    // stage A: f_ij tile (RBF + edge_emb), bf16. Lane covers row lane>>1
    // of the wave's 32 rows, 16 shorts at (lane&1)*16.
    {
        int elA = lane >> 1;                 // [0,32)
        int r0 = (lane & 1) * 16;
        float d  = __shfl(dv, elA);
        int   at = __shfl(atv, elA);
        const float* em = edge_emb + at * NR + r0;
        short v[16];
#pragma unroll
        for (int j = 0; j < 16; j++) {
            float off = (float)(r0 + j) * RBF_STEP;
            float dd = d - off;
            v[j] = f2bs(__expf(RBF_COEFF * dd * dd) + em[j]);
        }
        short* dst = &fA[(wid * 32 + elA) * EPAD + r0];
        *(bf16x8*)dst = *(bf16x8*)v;
        *(bf16x8*)(dst + 8) = *(bf16x8*)(v + 8);
    }

    // gathers for both subtiles (permuted xf): one bf16x8 per edge.
    // Latency hides under GEMM1 + ssp + H staging + GEMM2.
    bf16x8 xv[2][4];
    const unsigned short* xg = (const unsigned short*)xf;
#pragma unroll
    for (int s = 0; s < 2; s++) {
#pragma unroll
        for (int r = 0; r < 4; r++) {
            int jj = __shfl(jjv, s * 16 + quad * 4 + r);
            xv[s][r] = *(const bf16x8*)&xg[(size_t)jj * NB + col * 8];
        }
    }

    // wave-local LDS fence: fA writes -> GEMM1 reads
    asm volatile("s_waitcnt lgkmcnt(0)" ::: "memory");
    __builtin_amdgcn_sched_barrier(0);

    // GEMM1: hidden = f_ij @ W1 (K=32), weights loaded ONCE for 2 subtiles
    {
        bf16x8 b1f[8];
#pragma unroll
        for (int nt = 0; nt < 8; nt++)
            b1f[nt] = *(const bf16x8*)&W1T[(nt * 16 + col) * NR + quad * 8];
#pragma unroll
        for (int s = 0; s < 2; s++) {
            bf16x8 a1 = *(bf16x8*)&fA[(wid * 32 + s * 16 + col) * EPAD + quad * 8];
            f32x4 acc[8];
#pragma unroll
            for (int nt = 0; nt < 8; nt++)
                acc[nt] = __builtin_amdgcn_mfma_f32_16x16x32_bf16(a1, b1f[nt], (f32x4){0.f, 0.f, 0.f, 0.f}, 0, 0, 0);
#pragma unroll
            for (int nt = 0; nt < 8; nt++) {
                int n = nt * 16 + col;
                float bias = b1[n];
#pragma unroll
                for (int r = 0; r < 4; r++) {
                    int m = wid * 32 + s * 16 + quad * 4 + r;
                    H[m * HPAD + n] = f2bs(ssp_f(acc[nt][r] + bias));
                }
            }
        }
    }

    // wave-local LDS fence: H writes -> GEMM2 reads
    asm volatile("s_waitcnt lgkmcnt(0)" ::: "memory");
    __builtin_amdgcn_sched_barrier(0);

    // GEMM2: Wij = hidden @ W2 (K=128); each kt's B-fragments loaded ONCE
    // and consumed by both subtiles (halves W2T traffic).
    f32x4 acc2[2][8] = {};
#pragma unroll
    for (int kt = 0; kt < 4; kt++) {
        bf16x8 b2f[8];
#pragma unroll
        for (int nt = 0; nt < 8; nt++)
            b2f[nt] = *(const bf16x8*)&W2T[(nt * 16 + col) * NB + kt * 32 + quad * 8];
#pragma unroll
        for (int s = 0; s < 2; s++) {
            bf16x8 a = *(bf16x8*)&H[(wid * 32 + s * 16 + col) * HPAD + kt * 32 + quad * 8];
#pragma unroll
            for (int nt = 0; nt < 8; nt++)
                acc2[s][nt] = __builtin_amdgcn_mfma_f32_16x16x32_bf16(a, b2f[nt], acc2[s][nt], 0, 0, 0);
        }
    }

    // epilogue: per subtile, merge equal-atom runs over the quad's 4 edges,
    // flush merged runs with pk atomics (quad-uniform branches).
    float b2v[8];
#pragma unroll
    for (int nt = 0; nt < 8; nt++) b2v[nt] = b2[nt * 16 + col];

#pragma unroll
    for (int s = 0; s < 2; s++) {
        int e0l = s * 16 + quad * 4;
        int cur = __shfl(iiv, e0l);
        float accum[8] = {0.f, 0.f, 0.f, 0.f, 0.f, 0.f, 0.f, 0.f};
#pragma unroll
        for (int r = 0; r < 4; r++) {
            int ii = __shfl(iiv, e0l + r);
            float rc = __shfl(rcv, e0l + r);
            if (ii != cur) {
                flush_pk(agg + (size_t)cur * NB, accum, col);
#pragma unroll
                for (int nt = 0; nt < 8; nt++) accum[nt] = 0.f;
                cur = ii;
            }
#pragma unroll
            for (int nt = 0; nt < 8; nt++) {
                float w = (acc2[s][nt][r] + b2v[nt]) * rc;
                accum[nt] = fmaf(w, bs2f((unsigned short)xv[s][r][nt]), accum[nt]);
            }
        }
        flush_pk(agg + (size_t)cur * NB, accum, col);
    }
}

// ---------------------------------------------------------------------------
extern "C" void kernel_launch(void* const* d_in, const int* in_sizes, int n_in,
                              void* d_out, int out_size, void* d_ws, size_t ws_size,
                              hipStream_t stream) {
    const int*   z        = (const int*)d_in[0];
    const int*   z_res    = (const int*)d_in[1];
    const float* pos      = (const float*)d_in[2];
    const int*   idx_i    = (const int*)d_in[3];
    const int*   idx_j    = (const int*)d_in[4];
    const int*   edge_attr= (const int*)d_in[5];
    const int*   batch    = (const int*)d_in[6];
    const float* ele_emb  = (const float*)d_in[7];
    const float* res_emb  = (const float*)d_in[8];
    const float* edge_emb = (const float*)d_in[9];
    const float* in2f_W   = (const float*)d_in[10];
    const float* filt_W1  = (const float*)d_in[11];
    const float* filt_b1  = (const float*)d_in[12];
    const float* filt_W2  = (const float*)d_in[13];
    const float* filt_b2  = (const float*)d_in[14];
    const float* f2out_W1 = (const float*)d_in[15];
    const float* f2out_b1 = (const float*)d_in[16];
    const float* f2out_W2 = (const float*)d_in[17];
    const float* f2out_b2 = (const float*)d_in[18];
    const float* head_W1  = (const float*)d_in[19];
    const float* head_b1  = (const float*)d_in[20];
    const float* head_W2  = (const float*)d_in[21];

    const int N = in_sizes[0];
    const int E = in_sizes[3];

    char* p = (char*)d_ws;
    size_t off = 0;
    auto carve = [&](size_t bytes) -> void* {
        void* q = p + off;
        off = (off + bytes + 255) & ~(size_t)255;
        return q;
    };
    float*  d_d      = (float*)carve((size_t)E * 4);
    float4* edata    = (float4*)carve((size_t)E * 16);
    int*    sIarr    = (int*)carve((size_t)E * 4);
    int*    hist     = (int*)carve((size_t)N * 4);
    int*    cursor   = (int*)carve((size_t)N * 4);
    int*    partial  = (int*)carve((size_t)SCB * 4);
    float*  x_buf    = (float*)carve((size_t)N * NB * 4);
    short*  xf_buf   = (short*)carve((size_t)N * NB * 2);
    short*  agg      = (short*)carve((size_t)N * NB * 2);
    short*  in2f_WT  = (short*)carve((size_t)6 * NB * NB * 2);
    short*  fW1T     = (short*)carve((size_t)6 * NR * NB * 2);
    short*  fW2T     = (short*)carve((size_t)6 * NB * NB * 2);
    short*  oW1T     = (short*)carve((size_t)6 * NB * NB * 2);
    short*  oW2T     = (short*)carve((size_t)6 * NB * NB * 2);
    short*  hW1T     = (short*)carve((size_t)NB * NB * 2);
    (void)ws_size;

    // weight prep (bf16 transposed)
    {
        int tot = 6 * NB * NB;
        transpose_cvt<<<(tot + 255) / 256, 256, 0, stream>>>(in2f_W, in2f_WT, NB, NB, tot);
        transpose_cvt<<<(tot + 255) / 256, 256, 0, stream>>>(filt_W2, fW2T, NB, NB, tot);
        transpose_cvt<<<(tot + 255) / 256, 256, 0, stream>>>(f2out_W1, oW1T, NB, NB, tot);
        transpose_cvt<<<(tot + 255) / 256, 256, 0, stream>>>(f2out_W2, oW2T, NB, NB, tot);
        int tot1 = 6 * NR * NB;
        transpose_cvt<<<(tot1 + 255) / 256, 256, 0, stream>>>(filt_W1, fW1T, NR, NB, tot1);
        int tot2 = NB * NB;
        transpose_cvt<<<(tot2 + 255) / 256, 256, 0, stream>>>(head_W1, hW1T, NB, NB, tot2);
    }

    // edge prep + idx_i-grouped sort with packed records
    hipMemsetAsync(hist, 0, (size_t)N * 4, stream);
    int nblk_e4 = (E + 1023) / 1024;
    edge_prep4<<<nblk_e4, 256, 0, stream>>>(pos, idx_i, idx_j, d_d, hist, E);
    // multi-block exclusive scan: hist -> cursor (r22)
    scan_reduce<<<SCB, 256, 0, stream>>>(hist, partial, N);
    scan_partials<<<1, SCB, 0, stream>>>(partial);
    scan_expand<<<SCB, 256, 0, stream>>>(hist, partial, cursor, N);
    scatter_sorted4<<<nblk_e4, 256, 0, stream>>>(d_d, idx_i, idx_j, edge_attr,
                                                 cursor, edata, sIarr, E);
    // cursor[a] is now the END of atom a's sorted range; cursor[N-1] = count.

    atom_embed<<<(N * NB + 255) / 256, 256, 0, stream>>>(z, z_res, ele_emb, res_emb, x_buf, N);

    int nblk_atom64 = (N + 63) / 64;
    int nblk_edge = (E + 127) / 128;

    node_in2f_mfma<<<nblk_atom64, 256, 0, stream>>>(x_buf, in2f_WT, xf_buf, N);
    hipMemsetAsync(d_out, 0, (size_t)out_size * sizeof(float), stream);
    hipMemsetAsync(agg, 0, (size_t)N * NB * 2, stream);   // once; node_fused re-zeroes
    for (int i = 0; i < 6; i++) {
        edge_fused_mfma<<<nblk_edge, 256, 0, stream>>>(
            edata, sIarr, cursor, N, edge_emb,
            fW1T + (size_t)i * NR * NB, filt_b1 + (size_t)i * NB,
            fW2T + (size_t)i * NB * NB, filt_b2 + (size_t)i * NB,
            xf_buf, agg);
        if (i < 5) {
            node_fused_mfma<<<nblk_atom64, 256, 0, stream>>>(
                agg, oW1T + (size_t)i * NB * NB, f2out_b1 + (size_t)i * NB,
                oW2T + (size_t)i * NB * NB, f2out_b2 + (size_t)i * NB,
                in2f_WT + (size_t)(i + 1) * NB * NB,
                x_buf, xf_buf, N);
        } else {
            node_out_head_mfma<<<nblk_atom64, 256, 0, stream>>>(
                agg, oW1T + (size_t)i * NB * NB, f2out_b1 + (size_t)i * NB,
                oW2T + (size_t)i * NB * NB, f2out_b2 + (size_t)i * NB,
                x_buf, batch, hW1T, head_b1, head_W2,
                (float*)d_out, N);
        }
    }
}

// Round 10
// 1875.481 us; speedup vs baseline: 1.6428x; 1.0256x over previous
//
#include <hip/hip_runtime.h>
#include <hip/hip_bf16.h>
#include <math.h>

#define NB 128
#define NR 32
#define EPAD 40    // fA row stride in shorts
#define HPAD 136   // H/XA row stride in shorts (272B, 16B-aligned rows)
#define SCB 256    // scan blocks

// r25: 2-subtile node_fused (r24's confirmed lever applied to node path).
// r24 CONFIRMED weight-refetch theory: edge 228->176us (-23%), total
// 2207->1923, VALU 34->42.5, Mfma 5->6.4. Node budget now ~105us/dispatch
// vs 29us HBM roofline -- same disease (each wave fetches 96KB of weights
// for 16 rows). r25: node_fused = 128 threads / 2 waves per 64-atom block;
// wave owns 32 atoms as two M=16 subtiles; per-kt weight fragments loaded
// once, used by both subtiles (all 3 GEMMs); staging wave-local -> all
// barriers replaced by lgkmcnt fences. LDS unchanged 34.8KB. Edge kernel
// = r24 (176us, verified). r22 fast-scan retained.
// Falsified: r5 LDS gather staging, r6 owner-computes fusion, r7 permuted
// scatter, r10 pre-barrier gather, r12 analytic A-fragment, r14 2-tile
// pipeline, r16 LDS fp32 agg, r17 bigger block (same per-wave M), r18
// cross-quad merge, r20/r21 dispatch split. Confirmed: r22 fast scan
// (-150us), r24 subtile weight reuse (-284us).

static constexpr float CUTOFF_F    = 10.0f;
static constexpr float RBF_STEP    = 10.0f / 31.0f;
static constexpr float RBF_COEFF   = -4.805f;           // -0.5/(10/31)^2
static constexpr float LOG2_F      = 0.69314718055994531f;
static constexpr float PI_OVER_CUT = 0.314159265358979f;

typedef __attribute__((ext_vector_type(8))) short bf16x8;
typedef __attribute__((ext_vector_type(2))) short bf16x2;
typedef __attribute__((ext_vector_type(4))) float f32x4;

__device__ __forceinline__ short f2bs(float x) {
    __hip_bfloat16 h = __float2bfloat16(x);   // RNE
    return *reinterpret_cast<short*>(&h);
}
__device__ __forceinline__ float bs2f(unsigned short u) {
    unsigned int v = ((unsigned int)u) << 16;
    return __uint_as_float(v);
}
__device__ __forceinline__ float ssp_f(float v) {
    return fmaxf(v, 0.0f) + __logf(1.0f + __expf(-fabsf(v))) - LOG2_F;
}
__device__ __forceinline__ float silu_f(float v) {
    return v / (1.0f + __expf(-v));
}

// packed bf16 atomic add (2 features per op)
__device__ __forceinline__ void atomic_pk_add_bf16(short* addr, float lo, float hi) {
#if __has_builtin(__builtin_amdgcn_global_atomic_fadd_v2bf16)
    typedef bf16x2 __attribute__((address_space(1))) *gptr;
    bf16x2 v;
    v[0] = f2bs(lo);
    v[1] = f2bs(hi);
    __builtin_amdgcn_global_atomic_fadd_v2bf16((gptr)(unsigned long long)addr, v);
#else
    unsigned int* w = (unsigned int*)addr;
    unsigned int old = *w, assumed;
    do {
        assumed = old;
        float fl = bs2f((unsigned short)(assumed & 0xffff)) + lo;
        float fh = bs2f((unsigned short)(assumed >> 16)) + hi;
        unsigned int nv = ((unsigned int)(unsigned short)f2bs(fh) << 16) |
                          (unsigned short)f2bs(fl);
        old = atomicCAS(w, assumed, nv);
    } while (old != assumed);
#endif
}

// flush one merged run: 8 accumulated features/lane -> 4 pk atomics/lane.
// Run boundaries are quad-uniform so the lane^1 shuffles pair active lanes.
__device__ __forceinline__ void flush_pk(short* aggrow, const float* accum, int col) {
    bool even = ((col & 1) == 0);
#pragma unroll
    for (int q = 0; q < 4; q++) {
        float a = accum[2 * q], b = accum[2 * q + 1];
        float pa = __shfl_xor(a, 1);   // feature (2q)*16 + (col^1)
        float pb = __shfl_xor(b, 1);
        int nbase = even ? (2 * q) * 16 + col : (2 * q + 1) * 16 + (col - 1);
        float lo = even ? a : pb;
        float hi = even ? pa : b;
        atomic_pk_add_bf16(aggrow + nbase, lo, hi);
    }
}

// ---------------------------------------------------------------------------
// Weight prep: dst[b][c][r] = bf16(src[b][r][c])
// ---------------------------------------------------------------------------
__global__ void transpose_cvt(const float* __restrict__ src, short* __restrict__ dst,
                              int R, int C, int total) {
    int t = blockIdx.x * blockDim.x + threadIdx.x;
    if (t >= total) return;
    int rc = R * C;
    int b = t / rc;
    int rem = t - b * rc;
    int c = rem / R;
    int r = rem - c * R;
    dst[t] = f2bs(src[(size_t)b * rc + (size_t)r * C + c]);
}

// ---------------------------------------------------------------------------
// Edge prep: distances + per-atom histogram. 4 edges/thread for MLP.
// ---------------------------------------------------------------------------
__global__ void edge_prep4(const float* __restrict__ pos,
                           const int* __restrict__ idx_i,
                           const int* __restrict__ idx_j,
                           float* __restrict__ d_ij,
                           int* __restrict__ hist,
                           int E) {
    int b0 = blockIdx.x * 1024 + threadIdx.x;
    int ia[4], ib[4];
    bool val[4];
#pragma unroll
    for (int k = 0; k < 4; k++) {
        int e = b0 + k * 256;
        val[k] = (e < E);
        ia[k] = val[k] ? idx_i[e] : 0;
        ib[k] = val[k] ? idx_j[e] : 0;
    }
    float ax[4], ay[4], az[4], bx[4], by[4], bz[4];
#pragma unroll
    for (int k = 0; k < 4; k++) {
        const float* pa = pos + ia[k] * 3;
        ax[k] = pa[0]; ay[k] = pa[1]; az[k] = pa[2];
    }
#pragma unroll
    for (int k = 0; k < 4; k++) {
        const float* pb = pos + ib[k] * 3;
        bx[k] = pb[0]; by[k] = pb[1]; bz[k] = pb[2];
    }
#pragma unroll
    for (int k = 0; k < 4; k++) {
        if (!val[k]) continue;
        float dx = ax[k] - bx[k], dy = ay[k] - by[k], dz = az[k] - bz[k];
        float d = sqrtf(dx * dx + dy * dy + dz * dz);
        d_ij[b0 + k * 256] = d;
        if (d < CUTOFF_F) atomicAdd(&hist[ia[k]], 1);
    }
}

// ---------------------------------------------------------------------------
// Multi-block exclusive scan of hist[N] -> cursor[N]  (r22, ~12us).
// ---------------------------------------------------------------------------
__global__ __launch_bounds__(256) void scan_reduce(const int* __restrict__ hist,
                                                   int* __restrict__ partial, int N) {
    __shared__ int red[256];
    int b = blockIdx.x;
    int chunk = (N + SCB - 1) / SCB;
    int lo = b * chunk;
    int hi = min(lo + chunk, N);
    int s = 0;
    for (int i = lo + threadIdx.x; i < hi; i += 256) s += hist[i];
    red[threadIdx.x] = s;
    __syncthreads();
    for (int d = 128; d > 0; d >>= 1) {
        if (threadIdx.x < d) red[threadIdx.x] += red[threadIdx.x + d];
        __syncthreads();
    }
    if (threadIdx.x == 0) partial[b] = red[0];
}

__global__ __launch_bounds__(256) void scan_partials(int* __restrict__ partial) {
    __shared__ int sm[SCB];
    int t = threadIdx.x;
    sm[t] = partial[t];
    __syncthreads();
    for (int d = 1; d < SCB; d <<= 1) {
        int v = (t >= d) ? sm[t - d] : 0;
        __syncthreads();
        sm[t] += v;
        __syncthreads();
    }
    partial[t] = (t == 0) ? 0 : sm[t - 1];   // exclusive
}

__global__ __launch_bounds__(256) void scan_expand(const int* __restrict__ hist,
                                                   const int* __restrict__ partial,
                                                   int* __restrict__ cursor, int N) {
    __shared__ int tsum[256];
    int b = blockIdx.x;
    int chunk = (N + SCB - 1) / SCB;
    int lo = b * chunk;
    int hi = min(lo + chunk, N);
    int sub = (chunk + 255) / 256;
    int tlo = lo + threadIdx.x * sub;
    int thi = min(tlo + sub, hi);
    int s = 0;
    for (int i = tlo; i < thi; i++) s += hist[i];
    int t = threadIdx.x;
    tsum[t] = s;
    __syncthreads();
    for (int d = 1; d < 256; d <<= 1) {
        int v = (t >= d) ? tsum[t - d] : 0;
        __syncthreads();
        tsum[t] += v;
        __syncthreads();
    }
    int run = partial[b] + ((t == 0) ? 0 : tsum[t - 1]);
    for (int i = tlo; i < thi; i++) {
        cursor[i] = run;
        run += hist[i];
    }
}

// ---------------------------------------------------------------------------
// Scatter active edges into idx_i-grouped order. 4 edges/thread for MLP.
// Computes rcut for active edges only. After: cursor[a] == end of range.
// ---------------------------------------------------------------------------
__global__ void scatter_sorted4(const float* __restrict__ d_ij,
                                const int* __restrict__ idx_i,
                                const int* __restrict__ idx_j,
                                const int* __restrict__ edge_attr,
                                int* __restrict__ cursor,
                                float4* __restrict__ edata,
                                int* __restrict__ sIarr, int E) {
    int b0 = blockIdx.x * 1024 + threadIdx.x;
    float d[4]; int ii[4], jj[4], at[4]; bool act[4];
#pragma unroll
    for (int k = 0; k < 4; k++) {
        int e = b0 + k * 256;
        bool v = (e < E);
        d[k] = v ? d_ij[e] : 1e9f;
        act[k] = (d[k] < CUTOFF_F);
        ii[k] = act[k] ? idx_i[e] : 0;
        jj[k] = act[k] ? idx_j[e] : 0;
        at[k] = act[k] ? edge_attr[e] : 0;
    }
    int p[4];
#pragma unroll
    for (int k = 0; k < 4; k++)
        if (act[k]) p[k] = atomicAdd(&cursor[ii[k]], 1);
#pragma unroll
    for (int k = 0; k < 4; k++) {
        if (!act[k]) continue;
        float4 v;
        v.x = d[k];
        v.y = 0.5f * (__cosf(d[k] * PI_OVER_CUT) + 1.0f);
        v.z = __int_as_float(jj[k]);
        v.w = __int_as_float(at[k]);
        edata[p[k]] = v;
        sIarr[p[k]] = ii[k];
    }
}

// ---------------------------------------------------------------------------
// x = ele_emb[z] + res_emb[z_res]
// ---------------------------------------------------------------------------
__global__ void atom_embed(const int* __restrict__ z,
                           const int* __restrict__ z_res,
                           const float* __restrict__ ele_emb,
                           const float* __restrict__ res_emb,
                           float* __restrict__ x, int N) {
    int t = blockIdx.x * blockDim.x + threadIdx.x;
    if (t >= N * NB) return;
    int n = t >> 7, c = t & 127;
    x[t] = ele_emb[z[n] * NB + c] + res_emb[z_res[n] * NB + c];
}

// ---------------------------------------------------------------------------
// xf(bf16, permuted cols) = in(fp32) @ W  via MFMA. First-iteration in2f.
// ---------------------------------------------------------------------------
__global__ __launch_bounds__(256, 4) void node_in2f_mfma(
    const float* __restrict__ x, const short* __restrict__ WT,
    short* __restrict__ xf, int N) {
    __shared__ __align__(16) short XA[64 * HPAD];
    int a0 = blockIdx.x * 64;
    int t = threadIdx.x;
#pragma unroll
    for (int c = 0; c < 4; c++) {
        int chunk = t + c * 256;
        int row = chunk >> 4;
        int col = (chunk & 15) * 8;
        short v[8];
        if (a0 + row < N) {
            const float* src = x + (size_t)(a0 + row) * NB + col;
            float4 f0 = *(const float4*)src;
            float4 f1 = *(const float4*)(src + 4);
            v[0] = f2bs(f0.x); v[1] = f2bs(f0.y); v[2] = f2bs(f0.z); v[3] = f2bs(f0.w);
            v[4] = f2bs(f1.x); v[5] = f2bs(f1.y); v[6] = f2bs(f1.z); v[7] = f2bs(f1.w);
        } else {
#pragma unroll
            for (int j = 0; j < 8; j++) v[j] = 0;
        }
        *(bf16x8*)&XA[row * HPAD + col] = *(bf16x8*)v;
    }
    __syncthreads();

    int wid = t >> 6, lane = t & 63;
    int quad = lane >> 4, col = lane & 15;
    int mrow = wid * 16 + col;

    f32x4 acc[8] = {};
#pragma unroll
    for (int kt = 0; kt < 4; kt++) {
        bf16x8 a = *(bf16x8*)&XA[mrow * HPAD + kt * 32 + quad * 8];
#pragma unroll
        for (int nt = 0; nt < 8; nt++) {
            bf16x8 b = *(const bf16x8*)&WT[(nt * 16 + col) * NB + kt * 32 + quad * 8];
            acc[nt] = __builtin_amdgcn_mfma_f32_16x16x32_bf16(a, b, acc[nt], 0, 0, 0);
        }
    }
#pragma unroll
    for (int nt = 0; nt < 8; nt++) {
        int cst = col * 8 + nt;   // permuted storage col
#pragma unroll
        for (int r = 0; r < 4; r++) {
            int m = wid * 16 + quad * 4 + r;
            if (a0 + m < N) xf[(size_t)(a0 + m) * NB + cst] = f2bs(acc[nt][r]);
        }
    }
}

// ---------------------------------------------------------------------------
// 2-SUBTILE node_fused (r25): v = ssp(agg@W1+b1)@W2+b2 ; x += v ;
// xf_next(bf16, permuted) = x @ Wn. 128 threads / 2 waves per 64-atom
// block; wave owns 32 atoms as two M=16 subtiles; per-kt weight fragments
// loaded once per wave, consumed by both subtiles. Staging wave-local ->
// barrier-free (lgkmcnt fences). Re-zeroes its agg rows.
// ---------------------------------------------------------------------------
__global__ __launch_bounds__(128, 1) void node_fused_mfma(
    short* __restrict__ agg,
    const short* __restrict__ W1T, const float* __restrict__ b1,
    const short* __restrict__ W2T, const float* __restrict__ b2,
    const short* __restrict__ WnT,
    float* __restrict__ x, short* __restrict__ xf, int N) {
    __shared__ __align__(16) short XA[64 * HPAD];
    __shared__ __align__(16) short H[64 * HPAD];
    int a0 = blockIdx.x * 64;
    int t = threadIdx.x;                 // [0,128)
    int wid = t >> 6, lane = t & 63;     // 2 waves
    int quad = lane >> 4, col = lane & 15;

    // wave-local staging: wave wid stages its own rows [wid*32, wid*32+32)
#pragma unroll
    for (int c = 0; c < 8; c++) {
        int chunk = lane + c * 64;            // [0,512)
        int row = wid * 32 + (chunk >> 4);    // wave-local row
        int colb = (chunk & 15) * 8;
        bf16x8 v = {0, 0, 0, 0, 0, 0, 0, 0};
        if (a0 + row < N) {
            short* src = agg + (size_t)(a0 + row) * NB + colb;
            v = *(const bf16x8*)src;
            *(bf16x8*)src = (bf16x8){0, 0, 0, 0, 0, 0, 0, 0};  // re-zero
        }
        *(bf16x8*)&XA[row * HPAD + colb] = v;
    }
    asm volatile("s_waitcnt lgkmcnt(0)" ::: "memory");
    __builtin_amdgcn_sched_barrier(0);

    // GEMM1 + ssp -> H (2 subtiles, weights loaded once per kt)
    {
        f32x4 acc[2][8] = {};
#pragma unroll
        for (int kt = 0; kt < 4; kt++) {
            bf16x8 bf[8];
#pragma unroll
            for (int nt = 0; nt < 8; nt++)
                bf[nt] = *(const bf16x8*)&W1T[(nt * 16 + col) * NB + kt * 32 + quad * 8];
#pragma unroll
            for (int s = 0; s < 2; s++) {
                bf16x8 a = *(bf16x8*)&XA[(wid * 32 + s * 16 + col) * HPAD + kt * 32 + quad * 8];
#pragma unroll
                for (int nt = 0; nt < 8; nt++)
                    acc[s][nt] = __builtin_amdgcn_mfma_f32_16x16x32_bf16(a, bf[nt], acc[s][nt], 0, 0, 0);
            }
        }
#pragma unroll
        for (int s = 0; s < 2; s++) {
#pragma unroll
            for (int nt = 0; nt < 8; nt++) {
                int n = nt * 16 + col;
                float bias = b1[n];
#pragma unroll
                for (int r = 0; r < 4; r++) {
                    int m = wid * 32 + s * 16 + quad * 4 + r;
                    H[m * HPAD + n] = f2bs(ssp_f(acc[s][nt][r] + bias));
                }
            }
        }
    }
    asm volatile("s_waitcnt lgkmcnt(0)" ::: "memory");
    __builtin_amdgcn_sched_barrier(0);

    // GEMM2 + residual: x_new -> global fp32 + XA bf16 (reuse)
    {
        f32x4 acc[2][8] = {};
#pragma unroll
        for (int kt = 0; kt < 4; kt++) {
            bf16x8 bf[8];
#pragma unroll
            for (int nt = 0; nt < 8; nt++)
                bf[nt] = *(const bf16x8*)&W2T[(nt * 16 + col) * NB + kt * 32 + quad * 8];
#pragma unroll
            for (int s = 0; s < 2; s++) {
                bf16x8 a = *(bf16x8*)&H[(wid * 32 + s * 16 + col) * HPAD + kt * 32 + quad * 8];
#pragma unroll
                for (int nt = 0; nt < 8; nt++)
                    acc[s][nt] = __builtin_amdgcn_mfma_f32_16x16x32_bf16(a, bf[nt], acc[s][nt], 0, 0, 0);
            }
        }
#pragma unroll
        for (int s = 0; s < 2; s++) {
#pragma unroll
            for (int nt = 0; nt < 8; nt++) {
                int n = nt * 16 + col;
                float bias = b2[n];
#pragma unroll
                for (int r = 0; r < 4; r++) {
                    int m = wid * 32 + s * 16 + quad * 4 + r;
                    float xn = 0.0f;
                    if (a0 + m < N) {
                        size_t o = (size_t)(a0 + m) * NB + n;
                        xn = x[o] + acc[s][nt][r] + bias;
                        x[o] = xn;
                    }
                    XA[m * HPAD + n] = f2bs(xn);
                }
            }
        }
    }
    asm volatile("s_waitcnt lgkmcnt(0)" ::: "memory");
    __builtin_amdgcn_sched_barrier(0);

    // GEMM3: xf = x_new @ Wn  (bf16 out, permuted storage cols)
    {
        f32x4 acc[2][8] = {};
#pragma unroll
        for (int kt = 0; kt < 4; kt++) {
            bf16x8 bf[8];
#pragma unroll
            for (int nt = 0; nt < 8; nt++)
                bf[nt] = *(const bf16x8*)&WnT[(nt * 16 + col) * NB + kt * 32 + quad * 8];
#pragma unroll
            for (int s = 0; s < 2; s++) {
                bf16x8 a = *(bf16x8*)&XA[(wid * 32 + s * 16 + col) * HPAD + kt * 32 + quad * 8];
#pragma unroll
                for (int nt = 0; nt < 8; nt++)
                    acc[s][nt] = __builtin_amdgcn_mfma_f32_16x16x32_bf16(a, bf[nt], acc[s][nt], 0, 0, 0);
            }
        }
#pragma unroll
        for (int s = 0; s < 2; s++) {
#pragma unroll
            for (int nt = 0; nt < 8; nt++) {
                int cst = col * 8 + nt;
#pragma unroll
                for (int r = 0; r < 4; r++) {
                    int m = wid * 32 + s * 16 + quad * 4 + r;
                    if (a0 + m < N) xf[(size_t)(a0 + m) * NB + cst] = f2bs(acc[s][nt][r]);
                }
            }
        }
    }
}

// ---------------------------------------------------------------------------
// Last iteration fused with head: v = ssp(agg@W1+b1)@W2+b2 ; xn = x + v ;
// h = silu(xn/||xn||) ; silu(h@hW1+hb1)@hW2 ; segment-sum by batch.
// ---------------------------------------------------------------------------
__global__ __launch_bounds__(256, 4) void node_out_head_mfma(
    const short* __restrict__ agg,
    const short* __restrict__ W1T, const float* __restrict__ b1,
    const short* __restrict__ W2T, const float* __restrict__ b2,
    const float* __restrict__ x, const int* __restrict__ batch,
    const short* __restrict__ hW1T, const float* __restrict__ hb1,
    const float* __restrict__ hW2,
    float* __restrict__ out, int N) {
    __shared__ __align__(16) short XA[64 * HPAD];
    __shared__ __align__(16) short H[64 * HPAD];
    __shared__ int sbat[64];
    __shared__ float rowval[64];
    int a0 = blockIdx.x * 64;
    int t = threadIdx.x;

    if (t < 64) sbat[t] = (a0 + t < N) ? batch[a0 + t] : -1;
#pragma unroll
    for (int c = 0; c < 4; c++) {
        int chunk = t + c * 256;
        int row = chunk >> 4;
        int col = (chunk & 15) * 8;
        bf16x8 v = {0, 0, 0, 0, 0, 0, 0, 0};
        if (a0 + row < N) v = *(const bf16x8*)&agg[(size_t)(a0 + row) * NB + col];
        *(bf16x8*)&XA[row * HPAD + col] = v;
    }
    __syncthreads();

    int wid = t >> 6, lane = t & 63;
    int quad = lane >> 4, col = lane & 15;
    int mrow = wid * 16 + col;

    // GEMM1 + ssp -> H
    {
        f32x4 acc[8] = {};
#pragma unroll
        for (int kt = 0; kt < 4; kt++) {
            bf16x8 a = *(bf16x8*)&XA[mrow * HPAD + kt * 32 + quad * 8];
#pragma unroll
            for (int nt = 0; nt < 8; nt++) {
                bf16x8 b = *(const bf16x8*)&W1T[(nt * 16 + col) * NB + kt * 32 + quad * 8];
                acc[nt] = __builtin_amdgcn_mfma_f32_16x16x32_bf16(a, b, acc[nt], 0, 0, 0);
            }
        }
#pragma unroll
        for (int nt = 0; nt < 8; nt++) {
            int n = nt * 16 + col;
            float bias = b1[n];
#pragma unroll
            for (int r = 0; r < 4; r++) {
                int m = wid * 16 + quad * 4 + r;
                H[m * HPAD + n] = f2bs(ssp_f(acc[nt][r] + bias));
            }
        }
    }
    __syncthreads();

    // GEMM2 + residual in registers; row sums of squares via 16-lane shuffle
    float xnv[8][4];
    float ssq[4] = {0.f, 0.f, 0.f, 0.f};
    {
        f32x4 acc[8] = {};
#pragma unroll
        for (int kt = 0; kt < 4; kt++) {
            bf16x8 a = *(bf16x8*)&H[mrow * HPAD + kt * 32 + quad * 8];
#pragma unroll
            for (int nt = 0; nt < 8; nt++) {
                bf16x8 b = *(const bf16x8*)&W2T[(nt * 16 + col) * NB + kt * 32 + quad * 8];
                acc[nt] = __builtin_amdgcn_mfma_f32_16x16x32_bf16(a, b, acc[nt], 0, 0, 0);
            }
        }
#pragma unroll
        for (int nt = 0; nt < 8; nt++) {
            int n = nt * 16 + col;
            float bias = b2[n];
#pragma unroll
            for (int r = 0; r < 4; r++) {
                int m = wid * 16 + quad * 4 + r;
                float xn = 0.0f;
                if (a0 + m < N) xn = x[(size_t)(a0 + m) * NB + n] + acc[nt][r] + bias;
                xnv[nt][r] = xn;
                ssq[r] += xn * xn;
            }
        }
    }
#pragma unroll
    for (int r = 0; r < 4; r++) {
#pragma unroll
        for (int m = 1; m < 16; m <<= 1) ssq[r] += __shfl_xor(ssq[r], m);
    }
    float inv[4];
#pragma unroll
    for (int r = 0; r < 4; r++) inv[r] = 1.0f / fmaxf(sqrtf(ssq[r]), 1e-12f);
    __syncthreads();
#pragma unroll
    for (int nt = 0; nt < 8; nt++) {
        int n = nt * 16 + col;
#pragma unroll
        for (int r = 0; r < 4; r++) {
            int m = wid * 16 + quad * 4 + r;
            XA[m * HPAD + n] = f2bs(silu_f(xnv[nt][r] * inv[r]));
        }
    }
    __syncthreads();

    // head GEMM: silu(h@hW1+hb1) dot hW2 per row
    f32x4 acc[8] = {};
#pragma unroll
    for (int kt = 0; kt < 4; kt++) {
        bf16x8 a = *(bf16x8*)&XA[mrow * HPAD + kt * 32 + quad * 8];
#pragma unroll
        for (int nt = 0; nt < 8; nt++) {
            bf16x8 b = *(const bf16x8*)&hW1T[(nt * 16 + col) * NB + kt * 32 + quad * 8];
            acc[nt] = __builtin_amdgcn_mfma_f32_16x16x32_bf16(a, b, acc[nt], 0, 0, 0);
        }
    }
    float partial[4] = {0.f, 0.f, 0.f, 0.f};
#pragma unroll
    for (int nt = 0; nt < 8; nt++) {
        int n = nt * 16 + col;
        float bias = hb1[n];
        float w2 = hW2[n];
#pragma unroll
        for (int r = 0; r < 4; r++) partial[r] += silu_f(acc[nt][r] + bias) * w2;
    }
#pragma unroll
    for (int r = 0; r < 4; r++) {
#pragma unroll
        for (int d = 1; d < 16; d <<= 1) partial[r] += __shfl_xor(partial[r], d);
    }
    if (col == 0) {
#pragma unroll
        for (int r = 0; r < 4; r++) rowval[wid * 16 + quad * 4 + r] = partial[r];
    }
    __syncthreads();

    if (t < 64) {
        int b = sbat[t];
        bool headf = (b >= 0) && (t == 0 || sbat[t - 1] != b);
        if (headf) {
            float s = 0.0f;
            int rr = t;
            while (rr < 64 && sbat[rr] == b) { s += rowval[rr]; rr++; }
            atomicAdd(&out[b], s);
        }
    }
}

// ---------------------------------------------------------------------------
// BARRIER-FREE 2-subtile edge kernel (r24, confirmed 176us). 128 edges/
// block, 4 waves, each wave owns 32 contiguous edges as two M=16 subtiles.
// Weight B-fragments loaded once per wave, reused by both subtiles.
// ---------------------------------------------------------------------------
__global__ __launch_bounds__(256, 3) void edge_fused_mfma(
    const float4* __restrict__ edata, const int* __restrict__ sIarr,
    const int* __restrict__ rowend, int natoms,
    const float* __restrict__ edge_emb,
    const short* __restrict__ W1T, const float* __restrict__ b1,
    const short* __restrict__ W2T, const float* __restrict__ b2,
    const short* __restrict__ xf, short* __restrict__ agg) {
    __shared__ __align__(16) short fA[128 * EPAD];
    __shared__ __align__(16) short H[128 * HPAD];

    int t = threadIdx.x;
    int wid = t >> 6, lane = t & 63;
    int quad = lane >> 4, col = lane & 15;
    int base = blockIdx.x * 128;
    int wbase = base + wid * 32;        // this wave's 32-edge window
    int el32 = lane & 31;               // lane holds record of edge wbase+el32

    // issue record loads immediately (edata/sIarr are E-sized)
    float4 ed = edata[wbase + el32];
    int sIv0 = sIarr[wbase + el32];
    int cnt = rowend[natoms - 1];
    if (base >= cnt) return;

    bool act = (wbase + el32) < cnt;
    float dv  = act ? ed.x : 1e9f;
    float rcv = act ? ed.y : 0.0f;
    int   jjv = act ? __float_as_int(ed.z) : 0;
    int   atv = act ? __float_as_int(ed.w) : 0;
    int   iiv = act ? sIv0 : 0;

    // stage A: f_ij tile (RBF + edge_emb), bf16. Lane covers row lane>>1
    // of the wave's 32 rows, 16 shorts at (lane&1)*16.
    {
        int elA = lane >> 1;                 // [0,32)
        int r0 = (lane & 1) * 16;
        float d  = __shfl(dv, elA);
        int   at = __shfl(atv, elA);
        const float* em = edge_emb + at * NR + r0;
        short v[16];
#pragma unroll
        for (int j = 0; j < 16; j++) {
            float off = (float)(r0 + j) * RBF_STEP;
            float dd = d - off;
            v[j] = f2bs(__expf(RBF_COEFF * dd * dd) + em[j]);
        }
        short* dst = &fA[(wid * 32 + elA) * EPAD + r0];
        *(bf16x8*)dst = *(bf16x8*)v;
        *(bf16x8*)(dst + 8) = *(bf16x8*)(v + 8);
    }

    // gathers for both subtiles (permuted xf): one bf16x8 per edge.
    // Latency hides under GEMM1 + ssp + H staging + GEMM2.
    bf16x8 xv[2][4];
    const unsigned short* xg = (const unsigned short*)xf;
#pragma unroll
    for (int s = 0; s < 2; s++) {
#pragma unroll
        for (int r = 0; r < 4; r++) {
            int jj = __shfl(jjv, s * 16 + quad * 4 + r);
            xv[s][r] = *(const bf16x8*)&xg[(size_t)jj * NB + col * 8];
        }
    }

    // wave-local LDS fence: fA writes -> GEMM1 reads
    asm volatile("s_waitcnt lgkmcnt(0)" ::: "memory");
    __builtin_amdgcn_sched_barrier(0);

    // GEMM1: hidden = f_ij @ W1 (K=32), weights loaded ONCE for 2 subtiles
    {
        bf16x8 b1f[8];
#pragma unroll
        for (int nt = 0; nt < 8; nt++)
            b1f[nt] = *(const bf16x8*)&W1T[(nt * 16 + col) * NR + quad * 8];
#pragma unroll
        for (int s = 0; s < 2; s++) {
            bf16x8 a1 = *(bf16x8*)&fA[(wid * 32 + s * 16 + col) * EPAD + quad * 8];
            f32x4 acc[8];
#pragma unroll
            for (int nt = 0; nt < 8; nt++)
                acc[nt] = __builtin_amdgcn_mfma_f32_16x16x32_bf16(a1, b1f[nt], (f32x4){0.f, 0.f, 0.f, 0.f}, 0, 0, 0);
#pragma unroll
            for (int nt = 0; nt < 8; nt++) {
                int n = nt * 16 + col;
                float bias = b1[n];
#pragma unroll
                for (int r = 0; r < 4; r++) {
                    int m = wid * 32 + s * 16 + quad * 4 + r;
                    H[m * HPAD + n] = f2bs(ssp_f(acc[nt][r] + bias));
                }
            }
        }
    }

    // wave-local LDS fence: H writes -> GEMM2 reads
    asm volatile("s_waitcnt lgkmcnt(0)" ::: "memory");
    __builtin_amdgcn_sched_barrier(0);

    // GEMM2: Wij = hidden @ W2 (K=128); each kt's B-fragments loaded ONCE
    // and consumed by both subtiles (halves W2T traffic).
    f32x4 acc2[2][8] = {};
#pragma unroll
    for (int kt = 0; kt < 4; kt++) {
        bf16x8 b2f[8];
#pragma unroll
        for (int nt = 0; nt < 8; nt++)
            b2f[nt] = *(const bf16x8*)&W2T[(nt * 16 + col) * NB + kt * 32 + quad * 8];
#pragma unroll
        for (int s = 0; s < 2; s++) {
            bf16x8 a = *(bf16x8*)&H[(wid * 32 + s * 16 + col) * HPAD + kt * 32 + quad * 8];
#pragma unroll
            for (int nt = 0; nt < 8; nt++)
                acc2[s][nt] = __builtin_amdgcn_mfma_f32_16x16x32_bf16(a, b2f[nt], acc2[s][nt], 0, 0, 0);
        }
    }

    // epilogue: per subtile, merge equal-atom runs over the quad's 4 edges,
    // flush merged runs with pk atomics (quad-uniform branches).
    float b2v[8];
#pragma unroll
    for (int nt = 0; nt < 8; nt++) b2v[nt] = b2[nt * 16 + col];

#pragma unroll
    for (int s = 0; s < 2; s++) {
        int e0l = s * 16 + quad * 4;
        int cur = __shfl(iiv, e0l);
        float accum[8] = {0.f, 0.f, 0.f, 0.f, 0.f, 0.f, 0.f, 0.f};
#pragma unroll
        for (int r = 0; r < 4; r++) {
            int ii = __shfl(iiv, e0l + r);
            float rc = __shfl(rcv, e0l + r);
            if (ii != cur) {
                flush_pk(agg + (size_t)cur * NB, accum, col);
#pragma unroll
                for (int nt = 0; nt < 8; nt++) accum[nt] = 0.f;
                cur = ii;
            }
#pragma unroll
            for (int nt = 0; nt < 8; nt++) {
                float w = (acc2[s][nt][r] + b2v[nt]) * rc;
                accum[nt] = fmaf(w, bs2f((unsigned short)xv[s][r][nt]), accum[nt]);
            }
        }
        flush_pk(agg + (size_t)cur * NB, accum, col);
    }
}

// ---------------------------------------------------------------------------
extern "C" void kernel_launch(void* const* d_in, const int* in_sizes, int n_in,
                              void* d_out, int out_size, void* d_ws, size_t ws_size,
                              hipStream_t stream) {
    const int*   z        = (const int*)d_in[0];
    const int*   z_res    = (const int*)d_in[1];
    const float* pos      = (const float*)d_in[2];
    const int*   idx_i    = (const int*)d_in[3];
    const int*   idx_j    = (const int*)d_in[4];
    const int*   edge_attr= (const int*)d_in[5];
    const int*   batch    = (const int*)d_in[6];
    const float* ele_emb  = (const float*)d_in[7];
    const float* res_emb  = (const float*)d_in[8];
    const float* edge_emb = (const float*)d_in[9];
    const float* in2f_W   = (const float*)d_in[10];
    const float* filt_W1  = (const float*)d_in[11];
    const float* filt_b1  = (const float*)d_in[12];
    const float* filt_W2  = (const float*)d_in[13];
    const float* filt_b2  = (const float*)d_in[14];
    const float* f2out_W1 = (const float*)d_in[15];
    const float* f2out_b1 = (const float*)d_in[16];
    const float* f2out_W2 = (const float*)d_in[17];
    const float* f2out_b2 = (const float*)d_in[18];
    const float* head_W1  = (const float*)d_in[19];
    const float* head_b1  = (const float*)d_in[20];
    const float* head_W2  = (const float*)d_in[21];

    const int N = in_sizes[0];
    const int E = in_sizes[3];

    char* p = (char*)d_ws;
    size_t off = 0;
    auto carve = [&](size_t bytes) -> void* {
        void* q = p + off;
        off = (off + bytes + 255) & ~(size_t)255;
        return q;
    };
    float*  d_d      = (float*)carve((size_t)E * 4);
    float4* edata    = (float4*)carve((size_t)E * 16);
    int*    sIarr    = (int*)carve((size_t)E * 4);
    int*    hist     = (int*)carve((size_t)N * 4);
    int*    cursor   = (int*)carve((size_t)N * 4);
    int*    partial  = (int*)carve((size_t)SCB * 4);
    float*  x_buf    = (float*)carve((size_t)N * NB * 4);
    short*  xf_buf   = (short*)carve((size_t)N * NB * 2);
    short*  agg      = (short*)carve((size_t)N * NB * 2);
    short*  in2f_WT  = (short*)carve((size_t)6 * NB * NB * 2);
    short*  fW1T     = (short*)carve((size_t)6 * NR * NB * 2);
    short*  fW2T     = (short*)carve((size_t)6 * NB * NB * 2);
    short*  oW1T     = (short*)carve((size_t)6 * NB * NB * 2);
    short*  oW2T     = (short*)carve((size_t)6 * NB * NB * 2);
    short*  hW1T     = (short*)carve((size_t)NB * NB * 2);
    (void)ws_size;

    // weight prep (bf16 transposed)
    {
        int tot = 6 * NB * NB;
        transpose_cvt<<<(tot + 255) / 256, 256, 0, stream>>>(in2f_W, in2f_WT, NB, NB, tot);
        transpose_cvt<<<(tot + 255) / 256, 256, 0, stream>>>(filt_W2, fW2T, NB, NB, tot);
        transpose_cvt<<<(tot + 255) / 256, 256, 0, stream>>>(f2out_W1, oW1T, NB, NB, tot);
        transpose_cvt<<<(tot + 255) / 256, 256, 0, stream>>>(f2out_W2, oW2T, NB, NB, tot);
        int tot1 = 6 * NR * NB;
        transpose_cvt<<<(tot1 + 255) / 256, 256, 0, stream>>>(filt_W1, fW1T, NR, NB, tot1);
        int tot2 = NB * NB;
        transpose_cvt<<<(tot2 + 255) / 256, 256, 0, stream>>>(head_W1, hW1T, NB, NB, tot2);
    }

    // edge prep + idx_i-grouped sort with packed records
    hipMemsetAsync(hist, 0, (size_t)N * 4, stream);
    int nblk_e4 = (E + 1023) / 1024;
    edge_prep4<<<nblk_e4, 256, 0, stream>>>(pos, idx_i, idx_j, d_d, hist, E);
    // multi-block exclusive scan: hist -> cursor (r22)
    scan_reduce<<<SCB, 256, 0, stream>>>(hist, partial, N);
    scan_partials<<<1, SCB, 0, stream>>>(partial);
    scan_expand<<<SCB, 256, 0, stream>>>(hist, partial, cursor, N);
    scatter_sorted4<<<nblk_e4, 256, 0, stream>>>(d_d, idx_i, idx_j, edge_attr,
                                                 cursor, edata, sIarr, E);
    // cursor[a] is now the END of atom a's sorted range; cursor[N-1] = count.

    atom_embed<<<(N * NB + 255) / 256, 256, 0, stream>>>(z, z_res, ele_emb, res_emb, x_buf, N);

    int nblk_atom64 = (N + 63) / 64;
    int nblk_edge = (E + 127) / 128;

    node_in2f_mfma<<<nblk_atom64, 256, 0, stream>>>(x_buf, in2f_WT, xf_buf, N);
    hipMemsetAsync(d_out, 0, (size_t)out_size * sizeof(float), stream);
    hipMemsetAsync(agg, 0, (size_t)N * NB * 2, stream);   // once; node_fused re-zeroes
    for (int i = 0; i < 6; i++) {
        edge_fused_mfma<<<nblk_edge, 256, 0, stream>>>(
            edata, sIarr, cursor, N, edge_emb,
            fW1T + (size_t)i * NR * NB, filt_b1 + (size_t)i * NB,
            fW2T + (size_t)i * NB * NB, filt_b2 + (size_t)i * NB,
            xf_buf, agg);
        if (i < 5) {
            node_fused_mfma<<<nblk_atom64, 128, 0, stream>>>(
                agg, oW1T + (size_t)i * NB * NB, f2out_b1 + (size_t)i * NB,
                oW2T + (size_t)i * NB * NB, f2out_b2 + (size_t)i * NB,
                in2f_WT + (size_t)(i + 1) * NB * NB,
                x_buf, xf_buf, N);
        } else {
            node_out_head_mfma<<<nblk_atom64, 256, 0, stream>>>(
                agg, oW1T + (size_t)i * NB * NB, f2out_b1 + (size_t)i * NB,
                oW2T + (size_t)i * NB * NB, f2out_b2 + (size_t)i * NB,
                x_buf, batch, hW1T, head_b1, head_W2,
                (float*)d_out, N);
        }
    }
}